// Round 1
// baseline (497.771 us; speedup 1.0000x reference)
//
#include <hip/hip_runtime.h>
#include <cstdint>

#define DEV __device__ __forceinline__

typedef __attribute__((ext_vector_type(8))) short bf16x8;
typedef __attribute__((ext_vector_type(4))) float f32x4;

static constexpr int B  = 64;
static constexpr int NI = 512;
static constexpr int NQ = 128;
static constexpr int D  = 640;
static constexpr int H  = 1280;
static constexpr float NEGV  = -65504.0f;
static constexpr float SCALE = 0.039528470752104745f; // 1/sqrt(640)

DEV unsigned short f2bf(float f) {
  union { float f; uint32_t u; } c; c.f = f;
  uint32_t u = c.u;
  u += 0x7fffu + ((u >> 16) & 1u);     // RTNE
  return (unsigned short)(u >> 16);
}
DEV float bf2f(unsigned short h) {
  union { uint32_t u; float f; } c; c.u = ((uint32_t)h) << 16;
  return c.f;
}

// async global->LDS, 16B per lane (CK-style addrspace casts)
DEV void gll16(const void* g, void* l) {
  __builtin_amdgcn_global_load_lds(
      (const __attribute__((address_space(1))) void*)(uintptr_t)g,
      (__attribute__((address_space(3))) void*)(uint32_t)(uintptr_t)l,
      16, 0, 0);
}

// stage a 128-row x 32-col bf16 tile (row-major, leading dim ld) into lds
DEV void stage_tile(const unsigned short* src, int ld, unsigned short* lds, int tid) {
  const int w = tid >> 6, lane = tid & 63;
#pragma unroll
  for (int i = 0; i < 2; ++i) {
    int c = w * 128 + i * 64 + lane;        // chunk 0..511, 16B each
    int r = c >> 2, kc = (c & 3) << 3;      // row, k-offset (8 bf16)
    gll16(src + (long)r * ld + kc, (char*)lds + (size_t)c * 16);
  }
}

// C(M,N) = A(M,K) @ Bt(N,K)^T ; all bf16 in, fp32 acc; OUT_BF16 selects store type
template<int OUT_BF16>
__global__ __launch_bounds__(256, 2) void gemm_nt(
    const unsigned short* __restrict__ A, const unsigned short* __restrict__ Bt,
    void* __restrict__ C, int lda, int ldb, int ldc, int K,
    long sA, long sB, long sC)
{
  __shared__ __align__(16) unsigned short lsA[128 * 32];
  __shared__ __align__(16) unsigned short lsB[128 * 32];
  const int tid = threadIdx.x;
  const int w = tid >> 6, lane = tid & 63;
  const int wm = w >> 1, wn = w & 1;
  const int g = lane >> 4, r = lane & 15;
  const long zb = blockIdx.z;
  const unsigned short* Ab = A + zb * sA + (long)blockIdx.x * 128 * lda;
  const unsigned short* Bb = Bt + zb * sB + (long)blockIdx.y * 128 * ldb;

  f32x4 acc[4][4] = {};
  for (int k0 = 0; k0 < K; k0 += 32) {
    stage_tile(Ab + k0, lda, lsA, tid);
    stage_tile(Bb + k0, ldb, lsB, tid);
    __syncthreads();                       // drains vmcnt before barrier
    bf16x8 af[4], bfr[4];
#pragma unroll
    for (int mi = 0; mi < 4; ++mi)
      af[mi] = *(const bf16x8*)&lsA[(wm * 64 + mi * 16 + r) * 32 + g * 8];
#pragma unroll
    for (int ni = 0; ni < 4; ++ni)
      bfr[ni] = *(const bf16x8*)&lsB[(wn * 64 + ni * 16 + r) * 32 + g * 8];
#pragma unroll
    for (int mi = 0; mi < 4; ++mi)
#pragma unroll
      for (int ni = 0; ni < 4; ++ni)
        acc[mi][ni] = __builtin_amdgcn_mfma_f32_16x16x32_bf16(af[mi], bfr[ni], acc[mi][ni], 0, 0, 0);
    __syncthreads();
  }
  const int row0 = blockIdx.x * 128 + wm * 64;
  const int col0 = blockIdx.y * 128 + wn * 64;
#pragma unroll
  for (int mi = 0; mi < 4; ++mi)
#pragma unroll
    for (int ni = 0; ni < 4; ++ni)
#pragma unroll
      for (int j = 0; j < 4; ++j) {
        int rr = row0 + mi * 16 + g * 4 + j;   // D layout: row=(lane>>4)*4+reg
        int cc = col0 + ni * 16 + r;           //           col=lane&15
        float v = acc[mi][ni][j];
        if (OUT_BF16)
          ((unsigned short*)C)[zb * sC + (long)rr * ldc + cc] = f2bf(v);
        else
          ((float*)C)[zb * sC + (long)rr * ldc + cc] = v;
      }
}

// fused attflat MLP: logit[m] += sum_n relu(A@W1t^T + b1)[m,n] * W2[n]
// grid: (Mtiles, H/128); atomicAdd accumulation across n-chunks
__global__ __launch_bounds__(256, 2) void hatt_k(
    const unsigned short* __restrict__ A, const unsigned short* __restrict__ Bt,
    const float* __restrict__ b1, const float* __restrict__ W2,
    float* __restrict__ outlogit)
{
  __shared__ __align__(16) unsigned short lsA[128 * 32];
  __shared__ __align__(16) unsigned short lsB[128 * 32];
  __shared__ float b1c[128], w2c[128];
  const int tid = threadIdx.x;
  const int w = tid >> 6, lane = tid & 63;
  const int wm = w >> 1, wn = w & 1;
  const int g = lane >> 4, r = lane & 15;
  const int m0 = blockIdx.x * 128;
  const int n0 = blockIdx.y * 128;
  if (tid < 128) { b1c[tid] = b1[n0 + tid]; w2c[tid] = W2[n0 + tid]; }
  const unsigned short* Ab = A + (long)m0 * D;
  const unsigned short* Bb = Bt + (long)n0 * D;

  f32x4 acc[4][4] = {};
  for (int k0 = 0; k0 < D; k0 += 32) {
    stage_tile(Ab + k0, D, lsA, tid);
    stage_tile(Bb + k0, D, lsB, tid);
    __syncthreads();
    bf16x8 af[4], bfr[4];
#pragma unroll
    for (int mi = 0; mi < 4; ++mi)
      af[mi] = *(const bf16x8*)&lsA[(wm * 64 + mi * 16 + r) * 32 + g * 8];
#pragma unroll
    for (int ni = 0; ni < 4; ++ni)
      bfr[ni] = *(const bf16x8*)&lsB[(wn * 64 + ni * 16 + r) * 32 + g * 8];
#pragma unroll
    for (int mi = 0; mi < 4; ++mi)
#pragma unroll
      for (int ni = 0; ni < 4; ++ni)
        acc[mi][ni] = __builtin_amdgcn_mfma_f32_16x16x32_bf16(af[mi], bfr[ni], acc[mi][ni], 0, 0, 0);
    __syncthreads();
  }
  float rs[4][4];
#pragma unroll
  for (int mi = 0; mi < 4; ++mi)
#pragma unroll
    for (int j = 0; j < 4; ++j) rs[mi][j] = 0.f;
#pragma unroll
  for (int mi = 0; mi < 4; ++mi)
#pragma unroll
    for (int ni = 0; ni < 4; ++ni)
#pragma unroll
      for (int j = 0; j < 4; ++j) {
        int cl = wn * 64 + ni * 16 + r;
        float h = acc[mi][ni][j] + b1c[cl];
        h = fmaxf(h, 0.f);
        rs[mi][j] += h * w2c[cl];
      }
#pragma unroll
  for (int mi = 0; mi < 4; ++mi)
#pragma unroll
    for (int j = 0; j < 4; ++j) {
      float v = rs[mi][j];
      v += __shfl_xor(v, 1); v += __shfl_xor(v, 2);
      v += __shfl_xor(v, 4); v += __shfl_xor(v, 8);
      if (r == 0) atomicAdd(&outlogit[m0 + wm * 64 + mi * 16 + g * 4 + j], v);
    }
}

// masked row softmax over scores (one wave per row), writes bf16 P
template<int L>
__global__ void sm_scores(const float* __restrict__ S, const int* __restrict__ mask,
                          unsigned short* __restrict__ P, int M)
{
  constexpr int NV = L / 64;
  const int wid = threadIdx.x >> 6, lane = threadIdx.x & 63;
  const long row = (long)blockIdx.x * 4 + wid;
  const int b = (int)(row / M);
  const float* s = S + row * (long)L;
  const int* mk = mask + (long)b * L;
  float x[NV];
  float mx = -__builtin_inff();
#pragma unroll
  for (int i = 0; i < NV; ++i) {
    int idx = i * 64 + lane;
    float v = s[idx] * SCALE;
    x[i] = mk[idx] ? NEGV : v;
    mx = fmaxf(mx, x[i]);
  }
#pragma unroll
  for (int sft = 32; sft >= 1; sft >>= 1) mx = fmaxf(mx, __shfl_xor(mx, sft));
  float sum = 0.f;
#pragma unroll
  for (int i = 0; i < NV; ++i) { x[i] = __expf(x[i] - mx); sum += x[i]; }
#pragma unroll
  for (int sft = 32; sft >= 1; sft >>= 1) sum += __shfl_xor(sum, sft);
  const float inv = 1.f / sum;
  unsigned short* p = P + row * (long)L;
#pragma unroll
  for (int i = 0; i < NV; ++i) p[i * 64 + lane] = f2bf(x[i] * inv);
}

// attflat softmax over axis=1 (one block per batch); optionally mirrors to i_weight
template<int L>
__global__ void sm_att(const float* __restrict__ logit, const int* __restrict__ mask,
                       const float* __restrict__ b2p, float* __restrict__ att,
                       float* __restrict__ iw)
{
  constexpr int PER = (L + 255) / 256;
  __shared__ float red[4];
  const int tid = threadIdx.x, b = blockIdx.x;
  const float b2v = b2p[0];
  float xs[PER];
  float mx = -__builtin_inff();
#pragma unroll
  for (int i = 0; i < PER; ++i) {
    int idx = tid + i * 256;
    if (idx < L) {
      float v = mask[(long)b * L + idx] ? NEGV : (logit[(long)b * L + idx] + b2v);
      xs[i] = v; mx = fmaxf(mx, v);
    } else xs[i] = -__builtin_inff();
  }
#pragma unroll
  for (int s = 32; s >= 1; s >>= 1) mx = fmaxf(mx, __shfl_xor(mx, s));
  if ((tid & 63) == 0) red[tid >> 6] = mx;
  __syncthreads();
  mx = fmaxf(fmaxf(red[0], red[1]), fmaxf(red[2], red[3]));
  __syncthreads();
  float sum = 0.f;
#pragma unroll
  for (int i = 0; i < PER; ++i) {
    int idx = tid + i * 256;
    if (idx < L) { xs[i] = __expf(xs[i] - mx); sum += xs[i]; }
  }
#pragma unroll
  for (int s = 32; s >= 1; s >>= 1) sum += __shfl_xor(sum, s);
  if ((tid & 63) == 0) red[tid >> 6] = sum;
  __syncthreads();
  sum = red[0] + red[1] + red[2] + red[3];
  const float inv = 1.f / sum;
#pragma unroll
  for (int i = 0; i < PER; ++i) {
    int idx = tid + i * 256;
    if (idx < L) {
      float a = xs[i] * inv;
      att[(long)b * L + idx] = a;
      if (iw) iw[(long)b * L + idx] = a;
    }
  }
}

// pooled[b,d] = sum_m att[b,m] * X[b,m,d]   (block: 128 threads over d-chunk)
template<int L>
__global__ void pooled_k(const float* __restrict__ att, const unsigned short* __restrict__ X,
                         float* __restrict__ out)
{
  __shared__ float a[L];
  const int b = blockIdx.x, tid = threadIdx.x;
  const int d = blockIdx.y * 128 + tid;
  for (int i = tid; i < L; i += 128) a[i] = att[(long)b * L + i];
  __syncthreads();
  const unsigned short* xb = X + (long)b * L * D + d;
  float acc = 0.f;
#pragma unroll 4
  for (int m = 0; m < L; ++m) acc += a[m] * bf2f(xb[(long)m * D]);
  out[b * D + d] = acc;
}

// out[b,n] = sum_k pooled[b,k]*W[k,n] + bias[n]   (fp32 VALU, tiny GEMM)
__global__ void final_k(const float* __restrict__ pooled, const float* __restrict__ W,
                        const float* __restrict__ bias, float* __restrict__ out)
{
  __shared__ float p[D];
  const int b = blockIdx.x, tid = threadIdx.x;
  const int nn = blockIdx.y * 128 + tid;
  for (int i = tid; i < D; i += 128) p[i] = pooled[b * D + i];
  __syncthreads();
  float acc = bias[nn];
  for (int k = 0; k < D; ++k) acc += p[k] * W[(long)k * D + nn];
  out[b * D + nn] = acc;
}

__global__ void cast_bf_k(const float* __restrict__ in, unsigned short* __restrict__ out, long n4)
{
  const long i = (long)blockIdx.x * 256 + threadIdx.x;
  if (i < n4) {
    const float4 v = ((const float4*)in)[i];
    unsigned short* op = out + i * 4;
    op[0] = f2bf(v.x); op[1] = f2bf(v.y); op[2] = f2bf(v.z); op[3] = f2bf(v.w);
  }
}

// out(C,R) bf16 = transpose(in(R,C) f32); blockIdx.z batches (stride R*C)
__global__ void tcast_k(const float* __restrict__ in, unsigned short* __restrict__ out, int R, int C)
{
  __shared__ float t[32][33];
  const int tx = threadIdx.x, ty = threadIdx.y;
  const long base = (long)blockIdx.z * R * C;
  const float* ib = in + base;
  unsigned short* ob = out + base;
  const int c0 = blockIdx.x * 32, r0 = blockIdx.y * 32;
#pragma unroll
  for (int k = 0; k < 4; ++k)
    t[ty + k * 8][tx] = ib[(long)(r0 + ty + k * 8) * C + c0 + tx];
  __syncthreads();
#pragma unroll
  for (int k = 0; k < 4; ++k)
    ob[(long)(c0 + ty + k * 8) * R + r0 + tx] = f2bf(t[tx][ty + k * 8]);
}

extern "C" void kernel_launch(void* const* d_in, const int* in_sizes, int n_in,
                              void* d_out, int out_size, void* d_ws, size_t ws_size,
                              hipStream_t stream)
{
  (void)in_sizes; (void)n_in; (void)out_size; (void)ws_size;
  const float* i_batch = (const float*)d_in[0];
  const float* q_batch = (const float*)d_in[1];
  const int*   i_mask  = (const int*)d_in[2];
  const int*   q_mask  = (const int*)d_in[3];
  const float* lW1 = (const float*)d_in[4];
  const float* lb1 = (const float*)d_in[5];
  const float* lW2 = (const float*)d_in[6];
  const float* lb2 = (const float*)d_in[7];
  const float* lWm = (const float*)d_in[8];
  const float* lbm = (const float*)d_in[9];
  const float* iW1 = (const float*)d_in[10];
  const float* ib1 = (const float*)d_in[11];
  const float* iW2 = (const float*)d_in[12];
  const float* ib2 = (const float*)d_in[13];
  const float* iWm = (const float*)d_in[14];
  const float* ibm = (const float*)d_in[15];
  float* out_if = (float*)d_out;          // (64,640)
  float* out_lf = out_if + B * D;         // (64,640)
  float* out_iw = out_lf + B * D;         // (64,512)

  char* wp = (char*)d_ws;
  size_t off = 0;
  auto alloc = [&](size_t bytes) { void* p = wp + off; off += (bytes + 255) & ~(size_t)255; return p; };
  unsigned short* i_bf   = (unsigned short*)alloc((size_t)B * NI * D * 2);
  unsigned short* q_bf   = (unsigned short*)alloc((size_t)B * NQ * D * 2);
  unsigned short* x1_bf  = (unsigned short*)alloc((size_t)B * NI * D * 2);  // later reused as i_bfT
  unsigned short* q_bfT  = (unsigned short*)alloc((size_t)B * NQ * D * 2);  // later reused as x2_bf
  float*          scores = (float*)alloc((size_t)B * NI * NQ * 4);          // shared both dirs
  unsigned short* p_bf   = (unsigned short*)alloc((size_t)B * NI * NQ * 2); // shared both dirs
  unsigned short* lW1t   = (unsigned short*)alloc((size_t)H * D * 2);
  unsigned short* iW1t   = (unsigned short*)alloc((size_t)H * D * 2);
  float* logit1  = (float*)alloc((size_t)B * NI * 4);
  float* att1    = (float*)alloc((size_t)B * NI * 4);
  float* logit2  = (float*)alloc((size_t)B * NQ * 4);
  float* att2    = (float*)alloc((size_t)B * NQ * 4);
  float* pooled1 = (float*)alloc((size_t)B * D * 4);
  float* pooled2 = (float*)alloc((size_t)B * D * 4);
  unsigned short* i_bfT = x1_bf;   // written after pooled1 (x1 dead)
  unsigned short* x2_bf = q_bfT;   // written after G3 (q_bfT dead)

  // ---- prep: bf16 casts + transposes ----
  cast_bf_k<<<dim3((unsigned)((long)B * NI * D / 4 / 256)), 256, 0, stream>>>(i_batch, i_bf, (long)B * NI * D / 4);
  cast_bf_k<<<dim3((unsigned)((long)B * NQ * D / 4 / 256)), 256, 0, stream>>>(q_batch, q_bf, (long)B * NQ * D / 4);
  tcast_k<<<dim3(D / 32, NQ / 32, B), dim3(32, 8), 0, stream>>>(q_batch, q_bfT, NQ, D);
  tcast_k<<<dim3(H / 32, D / 32, 1), dim3(32, 8), 0, stream>>>(lW1, lW1t, D, H);
  tcast_k<<<dim3(H / 32, D / 32, 1), dim3(32, 8), 0, stream>>>(iW1, iW1t, D, H);

  // ---- direction 1: i_feat = attn(i_batch -> q_batch), attflat(lW*) ----
  gemm_nt<0><<<dim3(NI / 128, NQ / 128, B), 256, 0, stream>>>(
      i_bf, q_bf, scores, D, D, NQ, D, (long)NI * D, (long)NQ * D, (long)NI * NQ);
  sm_scores<NQ><<<dim3(B * NI / 4), 256, 0, stream>>>(scores, q_mask, p_bf, NI);
  gemm_nt<1><<<dim3(NI / 128, D / 128, B), 256, 0, stream>>>(
      p_bf, q_bfT, x1_bf, NQ, NQ, D, NQ, (long)NI * NQ, (long)D * NQ, (long)NI * D);
  hipMemsetAsync(logit1, 0, (size_t)B * NI * 4, stream);
  hatt_k<<<dim3(B * NI / 128, H / 128), 256, 0, stream>>>(x1_bf, lW1t, lb1, lW2, logit1);
  sm_att<NI><<<dim3(B), 256, 0, stream>>>(logit1, i_mask, lb2, att1, out_iw);
  pooled_k<NI><<<dim3(B, D / 128), 128, 0, stream>>>(att1, x1_bf, pooled1);
  final_k<<<dim3(B, D / 128), 128, 0, stream>>>(pooled1, lWm, lbm, out_if);

  // ---- direction 2: l_feat = attn(q_batch -> i_batch), attflat(iW*) ----
  tcast_k<<<dim3(D / 32, NI / 32, B), dim3(32, 8), 0, stream>>>(i_batch, i_bfT, NI, D);
  gemm_nt<0><<<dim3(NQ / 128, NI / 128, B), 256, 0, stream>>>(
      q_bf, i_bf, scores, D, D, NI, D, (long)NQ * D, (long)NI * D, (long)NQ * NI);
  sm_scores<NI><<<dim3(B * NQ / 4), 256, 0, stream>>>(scores, i_mask, p_bf, NQ);
  gemm_nt<1><<<dim3(NQ / 128, D / 128, B), 256, 0, stream>>>(
      p_bf, i_bfT, x2_bf, NI, NI, D, NI, (long)NQ * NI, (long)D * NI, (long)NQ * D);
  hipMemsetAsync(logit2, 0, (size_t)B * NQ * 4, stream);
  hatt_k<<<dim3(B * NQ / 128, H / 128), 256, 0, stream>>>(x2_bf, iW1t, ib1, iW2, logit2);
  sm_att<NQ><<<dim3(B), 256, 0, stream>>>(logit2, q_mask, ib2, att2, nullptr);
  pooled_k<NQ><<<dim3(B, D / 128), 128, 0, stream>>>(att2, x2_bf, pooled2);
  final_k<<<dim3(B, D / 128), 128, 0, stream>>>(pooled2, iWm, ibm, out_lf);
}

// Round 2
// 434.039 us; speedup vs baseline: 1.1468x; 1.1468x over previous
//
#include <hip/hip_runtime.h>
#include <cstdint>

#define DEV __device__ __forceinline__

typedef __attribute__((ext_vector_type(8))) short bf16x8;
typedef __attribute__((ext_vector_type(4))) float f32x4;

static constexpr int B  = 64;
static constexpr int NI = 512;
static constexpr int NQ = 128;
static constexpr int D  = 640;
static constexpr int H  = 1280;
static constexpr float NEGV  = -65504.0f;
static constexpr float SCALE = 0.039528470752104745f; // 1/sqrt(640)

DEV unsigned short f2bf(float f) {
  union { float f; uint32_t u; } c; c.f = f;
  uint32_t u = c.u;
  u += 0x7fffu + ((u >> 16) & 1u);     // RTNE
  return (unsigned short)(u >> 16);
}
DEV float bf2f(unsigned short h) {
  union { uint32_t u; float f; } c; c.u = ((uint32_t)h) << 16;
  return c.f;
}

// async global->LDS, 16B per lane
DEV void gll16(const void* g, void* l) {
  __builtin_amdgcn_global_load_lds(
      (const __attribute__((address_space(1))) void*)(uintptr_t)g,
      (__attribute__((address_space(3))) void*)(uint32_t)(uintptr_t)l,
      16, 0, 0);
}

// stage a 128-row x 64-col bf16 tile into LDS, XOR-swizzled source columns
// LDS[row][c] = G[row][c ^ (row&7)]  (c = 16B chunk index 0..7 within row)
DEV void stage64(const unsigned short* src, int ld, unsigned short* lds, int tid) {
  const int w = tid >> 6, lane = tid & 63;
#pragma unroll
  for (int i = 0; i < 4; ++i) {
    int c = w * 256 + i * 64 + lane;        // chunk 0..1023, 16B each
    int r = c >> 3, ck = c & 7;
    int col8 = ((ck ^ (r & 7)) << 3);       // pre-swizzled global column
    gll16(src + (long)r * ld + col8, (char*)lds + (size_t)c * 16);
  }
}

// swizzled fragment read: logical chunk q of row -> LDS chunk q^(row&7)
DEV bf16x8 frag(const unsigned short* ls, int row, int q) {
  return *(const bf16x8*)&ls[row * 64 + (((q ^ (row & 7))) << 3)];
}

// C(M,N) = A(M,K) @ Bt(N,K)^T ; bf16 in, fp32 acc; BK=64
template<int OUT_BF16>
__global__ __launch_bounds__(256, 2) void gemm_nt(
    const unsigned short* __restrict__ A, const unsigned short* __restrict__ Bt,
    void* __restrict__ C, int lda, int ldb, int ldc, int K,
    long sA, long sB, long sC)
{
  __shared__ __align__(16) unsigned short lsA[128 * 64];
  __shared__ __align__(16) unsigned short lsB[128 * 64];
  const int tid = threadIdx.x;
  const int w = tid >> 6, lane = tid & 63;
  const int wm = w >> 1, wn = w & 1;
  const int g = lane >> 4, r = lane & 15;
  const long zb = blockIdx.z;
  const unsigned short* Ab = A + zb * sA + (long)blockIdx.x * 128 * lda;
  const unsigned short* Bb = Bt + zb * sB + (long)blockIdx.y * 128 * ldb;

  f32x4 acc[4][4] = {};
  for (int k0 = 0; k0 < K; k0 += 64) {
    stage64(Ab + k0, lda, lsA, tid);
    stage64(Bb + k0, ldb, lsB, tid);
    __syncthreads();
#pragma unroll
    for (int kk = 0; kk < 2; ++kk) {
      bf16x8 af[4], bfr[4];
#pragma unroll
      for (int mi = 0; mi < 4; ++mi) af[mi]  = frag(lsA, wm * 64 + mi * 16 + r, kk * 4 + g);
#pragma unroll
      for (int ni = 0; ni < 4; ++ni) bfr[ni] = frag(lsB, wn * 64 + ni * 16 + r, kk * 4 + g);
#pragma unroll
      for (int mi = 0; mi < 4; ++mi)
#pragma unroll
        for (int ni = 0; ni < 4; ++ni)
          acc[mi][ni] = __builtin_amdgcn_mfma_f32_16x16x32_bf16(af[mi], bfr[ni], acc[mi][ni], 0, 0, 0);
    }
    __syncthreads();
  }
  const int row0 = blockIdx.x * 128 + wm * 64;
  const int col0 = blockIdx.y * 128 + wn * 64;
#pragma unroll
  for (int mi = 0; mi < 4; ++mi)
#pragma unroll
    for (int ni = 0; ni < 4; ++ni)
#pragma unroll
      for (int j = 0; j < 4; ++j) {
        int rr = row0 + mi * 16 + g * 4 + j;
        int cc = col0 + ni * 16 + r;
        float v = acc[mi][ni][j];
        if (OUT_BF16)
          ((unsigned short*)C)[zb * sC + (long)rr * ldc + cc] = f2bf(v);
        else
          ((float*)C)[zb * sC + (long)rr * ldc + cc] = v;
      }
}

// fused attflat MLP: logit[m] += sum_n relu(A@W1t^T + b1)[m,n] * W2[n]
// grid: (H/128 fast, Mtiles) so B-panel + A-tile stay L2-hot
__global__ __launch_bounds__(256, 2) void hatt_k(
    const unsigned short* __restrict__ A, const unsigned short* __restrict__ Bt,
    const float* __restrict__ b1, const float* __restrict__ W2,
    float* __restrict__ outlogit)
{
  __shared__ __align__(16) unsigned short lsA[128 * 64];
  __shared__ __align__(16) unsigned short lsB[128 * 64];
  __shared__ float b1c[128], w2c[128];
  const int tid = threadIdx.x;
  const int w = tid >> 6, lane = tid & 63;
  const int wm = w >> 1, wn = w & 1;
  const int g = lane >> 4, r = lane & 15;
  const int n0 = blockIdx.x * 128;
  const int m0 = blockIdx.y * 128;
  if (tid < 128) { b1c[tid] = b1[n0 + tid]; w2c[tid] = W2[n0 + tid]; }
  const unsigned short* Ab = A + (long)m0 * D;
  const unsigned short* Bb = Bt + (long)n0 * D;

  f32x4 acc[4][4] = {};
  for (int k0 = 0; k0 < D; k0 += 64) {
    stage64(Ab + k0, D, lsA, tid);
    stage64(Bb + k0, D, lsB, tid);
    __syncthreads();
#pragma unroll
    for (int kk = 0; kk < 2; ++kk) {
      bf16x8 af[4], bfr[4];
#pragma unroll
      for (int mi = 0; mi < 4; ++mi) af[mi]  = frag(lsA, wm * 64 + mi * 16 + r, kk * 4 + g);
#pragma unroll
      for (int ni = 0; ni < 4; ++ni) bfr[ni] = frag(lsB, wn * 64 + ni * 16 + r, kk * 4 + g);
#pragma unroll
      for (int mi = 0; mi < 4; ++mi)
#pragma unroll
        for (int ni = 0; ni < 4; ++ni)
          acc[mi][ni] = __builtin_amdgcn_mfma_f32_16x16x32_bf16(af[mi], bfr[ni], acc[mi][ni], 0, 0, 0);
    }
    __syncthreads();
  }
  float rs[4][4];
#pragma unroll
  for (int mi = 0; mi < 4; ++mi)
#pragma unroll
    for (int j = 0; j < 4; ++j) rs[mi][j] = 0.f;
#pragma unroll
  for (int mi = 0; mi < 4; ++mi)
#pragma unroll
    for (int ni = 0; ni < 4; ++ni)
#pragma unroll
      for (int j = 0; j < 4; ++j) {
        int cl = wn * 64 + ni * 16 + r;
        float h = acc[mi][ni][j] + b1c[cl];
        h = fmaxf(h, 0.f);
        rs[mi][j] += h * w2c[cl];
      }
#pragma unroll
  for (int mi = 0; mi < 4; ++mi)
#pragma unroll
    for (int j = 0; j < 4; ++j) {
      float v = rs[mi][j];
      v += __shfl_xor(v, 1); v += __shfl_xor(v, 2);
      v += __shfl_xor(v, 4); v += __shfl_xor(v, 8);
      if (r == 0) atomicAdd(&outlogit[m0 + wm * 64 + mi * 16 + g * 4 + j], v);
    }
}

// masked row softmax over scores (one wave per row), writes bf16 P
template<int L>
__global__ void sm_scores(const float* __restrict__ S, const int* __restrict__ mask,
                          unsigned short* __restrict__ P, int M)
{
  constexpr int NV = L / 64;
  const int wid = threadIdx.x >> 6, lane = threadIdx.x & 63;
  const long row = (long)blockIdx.x * 4 + wid;
  const int b = (int)(row / M);
  const float* s = S + row * (long)L;
  const int* mk = mask + (long)b * L;
  float x[NV];
  float mx = -__builtin_inff();
#pragma unroll
  for (int i = 0; i < NV; ++i) {
    int idx = i * 64 + lane;
    float v = s[idx] * SCALE;
    x[i] = mk[idx] ? NEGV : v;
    mx = fmaxf(mx, x[i]);
  }
#pragma unroll
  for (int sft = 32; sft >= 1; sft >>= 1) mx = fmaxf(mx, __shfl_xor(mx, sft));
  float sum = 0.f;
#pragma unroll
  for (int i = 0; i < NV; ++i) { x[i] = __expf(x[i] - mx); sum += x[i]; }
#pragma unroll
  for (int sft = 32; sft >= 1; sft >>= 1) sum += __shfl_xor(sum, sft);
  const float inv = 1.f / sum;
  unsigned short* p = P + row * (long)L;
#pragma unroll
  for (int i = 0; i < NV; ++i) p[i * 64 + lane] = f2bf(x[i] * inv);
}

// attflat softmax over axis=1 (one block per batch)
template<int L>
__global__ void sm_att(const float* __restrict__ logit, const int* __restrict__ mask,
                       const float* __restrict__ b2p, float* __restrict__ att,
                       float* __restrict__ iw)
{
  constexpr int PER = (L + 255) / 256;
  __shared__ float red[4];
  const int tid = threadIdx.x, b = blockIdx.x;
  const float b2v = b2p[0];
  float xs[PER];
  float mx = -__builtin_inff();
#pragma unroll
  for (int i = 0; i < PER; ++i) {
    int idx = tid + i * 256;
    if (idx < L) {
      float v = mask[(long)b * L + idx] ? NEGV : (logit[(long)b * L + idx] + b2v);
      xs[i] = v; mx = fmaxf(mx, v);
    } else xs[i] = -__builtin_inff();
  }
#pragma unroll
  for (int s = 32; s >= 1; s >>= 1) mx = fmaxf(mx, __shfl_xor(mx, s));
  if ((tid & 63) == 0) red[tid >> 6] = mx;
  __syncthreads();
  mx = fmaxf(fmaxf(red[0], red[1]), fmaxf(red[2], red[3]));
  __syncthreads();
  float sum = 0.f;
#pragma unroll
  for (int i = 0; i < PER; ++i) {
    int idx = tid + i * 256;
    if (idx < L) { xs[i] = __expf(xs[i] - mx); sum += xs[i]; }
  }
#pragma unroll
  for (int s = 32; s >= 1; s >>= 1) sum += __shfl_xor(sum, s);
  if ((tid & 63) == 0) red[tid >> 6] = sum;
  __syncthreads();
  sum = red[0] + red[1] + red[2] + red[3];
  const float inv = 1.f / sum;
#pragma unroll
  for (int i = 0; i < PER; ++i) {
    int idx = tid + i * 256;
    if (idx < L) {
      float a = xs[i] * inv;
      att[(long)b * L + idx] = a;
      if (iw) iw[(long)b * L + idx] = a;
    }
  }
}

// pooled[b,d] = sum_m att[b,m] * X[b,m,d]; 4-way m-split per block
template<int L>
__global__ void pooled_k(const float* __restrict__ att, const unsigned short* __restrict__ X,
                         float* __restrict__ out)
{
  __shared__ float a[L];
  __shared__ float part[4][64];
  const int b = blockIdx.x, tid = threadIdx.x;
  const int dcol = tid & 63, grp = tid >> 6;
  const int d = blockIdx.y * 64 + dcol;
  for (int i = tid; i < L; i += 256) a[i] = att[(long)b * L + i];
  __syncthreads();
  const unsigned short* xb = X + (long)b * L * D + d;
  float acc = 0.f;
  const int m0 = grp * (L / 4);
#pragma unroll 4
  for (int m = m0; m < m0 + L / 4; ++m) acc += a[m] * bf2f(xb[(long)m * D]);
  part[grp][dcol] = acc;
  __syncthreads();
  if (tid < 64)
    out[b * D + blockIdx.y * 64 + tid] = part[0][tid] + part[1][tid] + part[2][tid] + part[3][tid];
}

// out[b,n] += partial over k-slice of pooled[b,:]@W ; out pre-zeroed
__global__ void final_k(const float* __restrict__ pooled, const float* __restrict__ W,
                        const float* __restrict__ bias, float* __restrict__ out)
{
  __shared__ float p[160];
  const int b = blockIdx.x, tid = threadIdx.x;
  const int nn = blockIdx.y * 128 + tid;
  const int k0 = blockIdx.z * 160;
  for (int i = tid; i < 160; i += 128) p[i] = pooled[b * D + k0 + i];
  __syncthreads();
  float acc = (blockIdx.z == 0) ? bias[nn] : 0.f;
  for (int k = 0; k < 160; ++k) acc += p[k] * W[(long)(k0 + k) * D + nn];
  atomicAdd(&out[b * D + nn], acc);
}

// fused cast: read f32 tile once, emit row-major bf16 AND transposed bf16
__global__ void cast_t_k(const float* __restrict__ in, unsigned short* __restrict__ outN,
                         unsigned short* __restrict__ outT, int R, int C)
{
  __shared__ float t[32][33];
  const int tx = threadIdx.x, ty = threadIdx.y;
  const long base = (long)blockIdx.z * R * C;
  const float* ib = in + base;
  unsigned short* obN = outN + base;
  unsigned short* obT = outT + base;
  const int c0 = blockIdx.x * 32, r0 = blockIdx.y * 32;
#pragma unroll
  for (int k = 0; k < 4; ++k) {
    float v = ib[(long)(r0 + ty + k * 8) * C + c0 + tx];
    t[ty + k * 8][tx] = v;
    obN[(long)(r0 + ty + k * 8) * C + c0 + tx] = f2bf(v);
  }
  __syncthreads();
#pragma unroll
  for (int k = 0; k < 4; ++k)
    obT[(long)(c0 + ty + k * 8) * R + r0 + tx] = f2bf(t[tx][ty + k * 8]);
}

// transpose-cast only (weights)
__global__ void tcast_k(const float* __restrict__ in, unsigned short* __restrict__ out, int R, int C)
{
  __shared__ float t[32][33];
  const int tx = threadIdx.x, ty = threadIdx.y;
  const float* ib = in;
  unsigned short* ob = out;
  const int c0 = blockIdx.x * 32, r0 = blockIdx.y * 32;
#pragma unroll
  for (int k = 0; k < 4; ++k)
    t[ty + k * 8][tx] = ib[(long)(r0 + ty + k * 8) * C + c0 + tx];
  __syncthreads();
#pragma unroll
  for (int k = 0; k < 4; ++k)
    ob[(long)(c0 + ty + k * 8) * R + r0 + tx] = f2bf(t[tx][ty + k * 8]);
}

extern "C" void kernel_launch(void* const* d_in, const int* in_sizes, int n_in,
                              void* d_out, int out_size, void* d_ws, size_t ws_size,
                              hipStream_t stream)
{
  (void)in_sizes; (void)n_in; (void)out_size; (void)ws_size;
  const float* i_batch = (const float*)d_in[0];
  const float* q_batch = (const float*)d_in[1];
  const int*   i_mask  = (const int*)d_in[2];
  const int*   q_mask  = (const int*)d_in[3];
  const float* lW1 = (const float*)d_in[4];
  const float* lb1 = (const float*)d_in[5];
  const float* lW2 = (const float*)d_in[6];
  const float* lb2 = (const float*)d_in[7];
  const float* lWm = (const float*)d_in[8];
  const float* lbm = (const float*)d_in[9];
  const float* iW1 = (const float*)d_in[10];
  const float* ib1 = (const float*)d_in[11];
  const float* iW2 = (const float*)d_in[12];
  const float* ib2 = (const float*)d_in[13];
  const float* iWm = (const float*)d_in[14];
  const float* ibm = (const float*)d_in[15];
  float* out_if = (float*)d_out;          // (64,640)
  float* out_lf = out_if + B * D;         // (64,640)
  float* out_iw = out_lf + B * D;         // (64,512)

  char* wp = (char*)d_ws;
  size_t off = 0;
  auto alloc = [&](size_t bytes) { void* p = wp + off; off += (bytes + 255) & ~(size_t)255; return p; };
  unsigned short* i_bf   = (unsigned short*)alloc((size_t)B * NI * D * 2);
  unsigned short* i_bfT  = (unsigned short*)alloc((size_t)B * NI * D * 2);
  unsigned short* q_bf   = (unsigned short*)alloc((size_t)B * NQ * D * 2);
  unsigned short* q_bfT  = (unsigned short*)alloc((size_t)B * NQ * D * 2);
  unsigned short* x1_bf  = (unsigned short*)alloc((size_t)B * NI * D * 2);
  unsigned short* x2_bf  = (unsigned short*)alloc((size_t)B * NQ * D * 2);
  float*          scores = (float*)alloc((size_t)B * NI * NQ * 4);          // shared both dirs
  unsigned short* p_bf   = (unsigned short*)alloc((size_t)B * NI * NQ * 2); // shared both dirs
  unsigned short* lW1t   = (unsigned short*)alloc((size_t)H * D * 2);
  unsigned short* iW1t   = (unsigned short*)alloc((size_t)H * D * 2);
  float* logit1  = (float*)alloc((size_t)B * NI * 4);
  float* att1    = (float*)alloc((size_t)B * NI * 4);
  float* logit2  = (float*)alloc((size_t)B * NQ * 4);
  float* att2    = (float*)alloc((size_t)B * NQ * 4);
  float* pooled1 = (float*)alloc((size_t)B * D * 4);
  float* pooled2 = (float*)alloc((size_t)B * D * 4);

  // zero the atomic-accumulated outputs
  hipMemsetAsync(out_if, 0, (size_t)2 * B * D * 4, stream);
  hipMemsetAsync(logit1, 0, (size_t)B * NI * 4, stream);
  hipMemsetAsync(logit2, 0, (size_t)B * NQ * 4, stream);

  // ---- prep: fused cast+transpose (read inputs once) ----
  cast_t_k<<<dim3(D / 32, NI / 32, B), dim3(32, 8), 0, stream>>>(i_batch, i_bf, i_bfT, NI, D);
  cast_t_k<<<dim3(D / 32, NQ / 32, B), dim3(32, 8), 0, stream>>>(q_batch, q_bf, q_bfT, NQ, D);
  tcast_k<<<dim3(H / 32, D / 32), dim3(32, 8), 0, stream>>>(lW1, lW1t, D, H);
  tcast_k<<<dim3(H / 32, D / 32), dim3(32, 8), 0, stream>>>(iW1, iW1t, D, H);

  // ---- direction 1: i_feat = attn(i_batch -> q_batch), attflat(lW*) ----
  gemm_nt<0><<<dim3(NI / 128, NQ / 128, B), 256, 0, stream>>>(
      i_bf, q_bf, scores, D, D, NQ, D, (long)NI * D, (long)NQ * D, (long)NI * NQ);
  sm_scores<NQ><<<dim3(B * NI / 4), 256, 0, stream>>>(scores, q_mask, p_bf, NI);
  gemm_nt<1><<<dim3(NI / 128, D / 128, B), 256, 0, stream>>>(
      p_bf, q_bfT, x1_bf, NQ, NQ, D, NQ, (long)NI * NQ, (long)D * NQ, (long)NI * D);
  hatt_k<<<dim3(H / 128, B * NI / 128), 256, 0, stream>>>(x1_bf, lW1t, lb1, lW2, logit1);
  sm_att<NI><<<dim3(B), 256, 0, stream>>>(logit1, i_mask, lb2, att1, out_iw);
  pooled_k<NI><<<dim3(B, D / 64), 256, 0, stream>>>(att1, x1_bf, pooled1);
  final_k<<<dim3(B, D / 128, 4), 128, 0, stream>>>(pooled1, lWm, lbm, out_if);

  // ---- direction 2: l_feat = attn(q_batch -> i_batch), attflat(iW*) ----
  gemm_nt<0><<<dim3(NQ / 128, NI / 128, B), 256, 0, stream>>>(
      q_bf, i_bf, scores, D, D, NI, D, (long)NQ * D, (long)NI * D, (long)NQ * NI);
  sm_scores<NI><<<dim3(B * NQ / 4), 256, 0, stream>>>(scores, i_mask, p_bf, NQ);
  gemm_nt<1><<<dim3(NQ / 128, D / 128, B), 256, 0, stream>>>(
      p_bf, i_bfT, x2_bf, NI, NI, D, NI, (long)NQ * NI, (long)D * NI, (long)NQ * D);
  hatt_k<<<dim3(H / 128, B * NQ / 128), 256, 0, stream>>>(x2_bf, iW1t, ib1, iW2, logit2);
  sm_att<NQ><<<dim3(B), 256, 0, stream>>>(logit2, q_mask, ib2, att2, nullptr);
  pooled_k<NQ><<<dim3(B, D / 64), 256, 0, stream>>>(att2, x2_bf, pooled2);
  final_k<<<dim3(B, D / 128, 4), 128, 0, stream>>>(pooled2, iWm, ibm, out_lf);
}

// Round 3
// 427.785 us; speedup vs baseline: 1.1636x; 1.0146x over previous
//
#include <hip/hip_runtime.h>
#include <cstdint>

#define DEV __device__ __forceinline__

typedef __attribute__((ext_vector_type(8))) short bf16x8;
typedef __attribute__((ext_vector_type(4))) float f32x4;

static constexpr int B  = 64;
static constexpr int NI = 512;
static constexpr int NQ = 128;
static constexpr int D  = 640;
static constexpr int H  = 1280;
static constexpr float NEGV  = -65504.0f;
static constexpr float SCALE = 0.039528470752104745f; // 1/sqrt(640)

DEV unsigned short f2bf(float f) {
  union { float f; uint32_t u; } c; c.f = f;
  uint32_t u = c.u;
  u += 0x7fffu + ((u >> 16) & 1u);     // RTNE
  return (unsigned short)(u >> 16);
}
DEV float bf2f(unsigned short h) {
  union { uint32_t u; float f; } c; c.u = ((uint32_t)h) << 16;
  return c.f;
}

// XCD-chunked bijective swizzle (nwg must be %8==0): keeps consecutive work
// items on the same XCD so shared panels hit that XCD's L2.
DEV int xcd_swz(int bid, int nwg) {
  return (bid & 7) * (nwg >> 3) + (bid >> 3);
}

// async global->LDS, 16B per lane
DEV void gll16(const void* g, void* l) {
  __builtin_amdgcn_global_load_lds(
      (const __attribute__((address_space(1))) void*)(uintptr_t)g,
      (__attribute__((address_space(3))) void*)(uint32_t)(uintptr_t)l,
      16, 0, 0);
}

// stage a 128-row x 64-col bf16 tile into LDS, XOR-swizzled source columns
// LDS[row][c] = G[row][c ^ (row&7)]  (c = 16B chunk index 0..7 within row)
DEV void stage64(const unsigned short* src, int ld, unsigned short* lds, int tid) {
  const int w = tid >> 6, lane = tid & 63;
#pragma unroll
  for (int i = 0; i < 4; ++i) {
    int c = w * 256 + i * 64 + lane;        // chunk 0..1023, 16B each
    int r = c >> 3, ck = c & 7;
    int col8 = ((ck ^ (r & 7)) << 3);       // pre-swizzled global column
    gll16(src + (long)r * ld + col8, (char*)lds + (size_t)c * 16);
  }
}

// swizzled fragment read: logical chunk q of row -> LDS chunk q^(row&7)
DEV bf16x8 frag(const unsigned short* ls, int row, int q) {
  return *(const bf16x8*)&ls[row * 64 + (((q ^ (row & 7))) << 3)];
}

// C(M,N) = A(M,K) @ Bt(N,K)^T ; bf16 in, fp32 acc; BK=64; 1D grid + XCD swizzle
template<int OUT_BF16>
__global__ __launch_bounds__(256, 4) void gemm_nt(
    const unsigned short* __restrict__ A, const unsigned short* __restrict__ Bt,
    void* __restrict__ C, int lda, int ldb, int ldc, int K,
    long sA, long sB, long sC, int gx, int gy)
{
  __shared__ __align__(16) unsigned short lsA[128 * 64];
  __shared__ __align__(16) unsigned short lsB[128 * 64];
  const int tid = threadIdx.x;
  const int w = tid >> 6, lane = tid & 63;
  const int wm = w >> 1, wn = w & 1;
  const int g = lane >> 4, r = lane & 15;
  const int wg = xcd_swz(blockIdx.x, gridDim.x);
  const int bz = wg / (gx * gy);
  const int r2 = wg - bz * gx * gy;
  const int by = r2 / gx;
  const int bx = r2 - by * gx;
  const long zb = bz;
  const unsigned short* Ab = A + zb * sA + (long)bx * 128 * lda;
  const unsigned short* Bb = Bt + zb * sB + (long)by * 128 * ldb;

  f32x4 acc[4][4] = {};
  for (int k0 = 0; k0 < K; k0 += 64) {
    stage64(Ab + k0, lda, lsA, tid);
    stage64(Bb + k0, ldb, lsB, tid);
    __syncthreads();
#pragma unroll
    for (int kk = 0; kk < 2; ++kk) {
      bf16x8 af[4], bfr[4];
#pragma unroll
      for (int mi = 0; mi < 4; ++mi) af[mi]  = frag(lsA, wm * 64 + mi * 16 + r, kk * 4 + g);
#pragma unroll
      for (int ni = 0; ni < 4; ++ni) bfr[ni] = frag(lsB, wn * 64 + ni * 16 + r, kk * 4 + g);
#pragma unroll
      for (int mi = 0; mi < 4; ++mi)
#pragma unroll
        for (int ni = 0; ni < 4; ++ni)
          acc[mi][ni] = __builtin_amdgcn_mfma_f32_16x16x32_bf16(af[mi], bfr[ni], acc[mi][ni], 0, 0, 0);
    }
    __syncthreads();
  }
  const int row0 = bx * 128 + wm * 64;
  const int col0 = by * 128 + wn * 64;
#pragma unroll
  for (int mi = 0; mi < 4; ++mi)
#pragma unroll
    for (int ni = 0; ni < 4; ++ni)
#pragma unroll
      for (int j = 0; j < 4; ++j) {
        int rr = row0 + mi * 16 + g * 4 + j;
        int cc = col0 + ni * 16 + r;
        float v = acc[mi][ni][j];
        if (OUT_BF16)
          ((unsigned short*)C)[zb * sC + (long)rr * ldc + cc] = f2bf(v);
        else
          ((float*)C)[zb * sC + (long)rr * ldc + cc] = v;
      }
}

// fused dir-1 QK^T + masked softmax: P = softmax(mask(A@Bt^T * SCALE)) in bf16
// A = queries (B,NI,D), Bt = keys (B,NQ,D); NQ=128 fits one block tile.
__global__ __launch_bounds__(256, 2) void qksm_k(
    const unsigned short* __restrict__ A, const unsigned short* __restrict__ Bt,
    const int* __restrict__ mask, unsigned short* __restrict__ P)
{
  __shared__ __align__(16) float S[128 * 128];   // 64 KB, aliased for staging
  unsigned short* lsA = (unsigned short*)S;
  unsigned short* lsB = lsA + 128 * 64;
  const int tid = threadIdx.x;
  const int w = tid >> 6, lane = tid & 63;
  const int wm = w >> 1, wn = w & 1;
  const int g = lane >> 4, r = lane & 15;
  const int wg = xcd_swz(blockIdx.x, gridDim.x);
  const int mt = wg & 3, b = wg >> 2;
  const unsigned short* Ab = A + ((long)b * NI + (long)mt * 128) * D;
  const unsigned short* Bb = Bt + (long)b * NQ * D;

  f32x4 acc[4][4] = {};
  for (int k0 = 0; k0 < D; k0 += 64) {
    stage64(Ab + k0, D, lsA, tid);
    stage64(Bb + k0, D, lsB, tid);
    __syncthreads();
#pragma unroll
    for (int kk = 0; kk < 2; ++kk) {
      bf16x8 af[4], bfr[4];
#pragma unroll
      for (int mi = 0; mi < 4; ++mi) af[mi]  = frag(lsA, wm * 64 + mi * 16 + r, kk * 4 + g);
#pragma unroll
      for (int ni = 0; ni < 4; ++ni) bfr[ni] = frag(lsB, wn * 64 + ni * 16 + r, kk * 4 + g);
#pragma unroll
      for (int mi = 0; mi < 4; ++mi)
#pragma unroll
        for (int ni = 0; ni < 4; ++ni)
          acc[mi][ni] = __builtin_amdgcn_mfma_f32_16x16x32_bf16(af[mi], bfr[ni], acc[mi][ni], 0, 0, 0);
    }
    __syncthreads();
  }
  // scores -> LDS (scaled), bank-swizzled: word = rr*128 + (cc ^ ((rr&7)<<2))
#pragma unroll
  for (int mi = 0; mi < 4; ++mi)
#pragma unroll
    for (int ni = 0; ni < 4; ++ni)
#pragma unroll
      for (int j = 0; j < 4; ++j) {
        int rr = wm * 64 + mi * 16 + g * 4 + j;
        int cc = wn * 64 + ni * 16 + r;
        S[rr * 128 + (cc ^ ((rr & 7) << 2))] = acc[mi][ni][j] * SCALE;
      }
  __syncthreads();
  const int* mk = mask + (long)b * NQ;
  const int mk0 = mk[lane], mk1 = mk[lane + 64];
  // each wave handles 32 rows; row data = 2 elems/lane
  for (int t = 0; t < 32; ++t) {
    const int rr = w * 32 + t;
    const int off = (rr & 7) << 2;
    float x0 = mk0 ? NEGV : S[rr * 128 + (lane ^ off)];
    float x1 = mk1 ? NEGV : S[rr * 128 + ((lane + 64) ^ off)];
    float mx = fmaxf(x0, x1);
#pragma unroll
    for (int s = 32; s >= 1; s >>= 1) mx = fmaxf(mx, __shfl_xor(mx, s));
    float e0 = __expf(x0 - mx), e1 = __expf(x1 - mx);
    float sum = e0 + e1;
#pragma unroll
    for (int s = 32; s >= 1; s >>= 1) sum += __shfl_xor(sum, s);
    const float inv = 1.f / sum;
    unsigned short* pr = P + ((long)b * NI + (long)mt * 128 + rr) * NQ;
    pr[lane] = f2bf(e0 * inv);
    pr[lane + 64] = f2bf(e1 * inv);
  }
}

// fused attflat MLP: logit[m] += sum_n relu(A@W1t^T + b1)[m,n] * W2[n]
// 1D grid, n fastest (NH=10 tiles) + XCD swizzle so A-tiles are fetched once.
__global__ __launch_bounds__(256, 4) void hatt_k(
    const unsigned short* __restrict__ A, const unsigned short* __restrict__ Bt,
    const float* __restrict__ b1, const float* __restrict__ W2,
    float* __restrict__ outlogit)
{
  constexpr int NH = H / 128;
  __shared__ __align__(16) unsigned short lsA[128 * 64];
  __shared__ __align__(16) unsigned short lsB[128 * 64];
  __shared__ float b1c[128], w2c[128];
  const int tid = threadIdx.x;
  const int w = tid >> 6, lane = tid & 63;
  const int wm = w >> 1, wn = w & 1;
  const int g = lane >> 4, r = lane & 15;
  const int wg = xcd_swz(blockIdx.x, gridDim.x);
  const int n0 = (wg % NH) * 128;
  const int m0 = (wg / NH) * 128;
  if (tid < 128) { b1c[tid] = b1[n0 + tid]; w2c[tid] = W2[n0 + tid]; }
  const unsigned short* Ab = A + (long)m0 * D;
  const unsigned short* Bb = Bt + (long)n0 * D;

  f32x4 acc[4][4] = {};
  for (int k0 = 0; k0 < D; k0 += 64) {
    stage64(Ab + k0, D, lsA, tid);
    stage64(Bb + k0, D, lsB, tid);
    __syncthreads();
#pragma unroll
    for (int kk = 0; kk < 2; ++kk) {
      bf16x8 af[4], bfr[4];
#pragma unroll
      for (int mi = 0; mi < 4; ++mi) af[mi]  = frag(lsA, wm * 64 + mi * 16 + r, kk * 4 + g);
#pragma unroll
      for (int ni = 0; ni < 4; ++ni) bfr[ni] = frag(lsB, wn * 64 + ni * 16 + r, kk * 4 + g);
#pragma unroll
      for (int mi = 0; mi < 4; ++mi)
#pragma unroll
        for (int ni = 0; ni < 4; ++ni)
          acc[mi][ni] = __builtin_amdgcn_mfma_f32_16x16x32_bf16(af[mi], bfr[ni], acc[mi][ni], 0, 0, 0);
    }
    __syncthreads();
  }
  float rs[4][4];
#pragma unroll
  for (int mi = 0; mi < 4; ++mi)
#pragma unroll
    for (int j = 0; j < 4; ++j) rs[mi][j] = 0.f;
#pragma unroll
  for (int mi = 0; mi < 4; ++mi)
#pragma unroll
    for (int ni = 0; ni < 4; ++ni)
#pragma unroll
      for (int j = 0; j < 4; ++j) {
        int cl = wn * 64 + ni * 16 + r;
        float h = acc[mi][ni][j] + b1c[cl];
        h = fmaxf(h, 0.f);
        rs[mi][j] += h * w2c[cl];
      }
#pragma unroll
  for (int mi = 0; mi < 4; ++mi)
#pragma unroll
    for (int j = 0; j < 4; ++j) {
      float v = rs[mi][j];
      v += __shfl_xor(v, 1); v += __shfl_xor(v, 2);
      v += __shfl_xor(v, 4); v += __shfl_xor(v, 8);
      if (r == 0) atomicAdd(&outlogit[m0 + wm * 64 + mi * 16 + g * 4 + j], v);
    }
}

// masked row softmax over scores (one wave per row), writes bf16 P (dir 2)
template<int L>
__global__ void sm_scores(const float* __restrict__ S, const int* __restrict__ mask,
                          unsigned short* __restrict__ P, int M)
{
  constexpr int NV = L / 64;
  const int wid = threadIdx.x >> 6, lane = threadIdx.x & 63;
  const long row = (long)blockIdx.x * 4 + wid;
  const int b = (int)(row / M);
  const float* s = S + row * (long)L;
  const int* mk = mask + (long)b * L;
  float x[NV];
  float mx = -__builtin_inff();
#pragma unroll
  for (int i = 0; i < NV; ++i) {
    int idx = i * 64 + lane;
    float v = s[idx] * SCALE;
    x[i] = mk[idx] ? NEGV : v;
    mx = fmaxf(mx, x[i]);
  }
#pragma unroll
  for (int sft = 32; sft >= 1; sft >>= 1) mx = fmaxf(mx, __shfl_xor(mx, sft));
  float sum = 0.f;
#pragma unroll
  for (int i = 0; i < NV; ++i) { x[i] = __expf(x[i] - mx); sum += x[i]; }
#pragma unroll
  for (int sft = 32; sft >= 1; sft >>= 1) sum += __shfl_xor(sum, sft);
  const float inv = 1.f / sum;
  unsigned short* p = P + row * (long)L;
#pragma unroll
  for (int i = 0; i < NV; ++i) p[i * 64 + lane] = f2bf(x[i] * inv);
}

// attflat softmax over axis=1 (one block per batch)
template<int L>
__global__ void sm_att(const float* __restrict__ logit, const int* __restrict__ mask,
                       const float* __restrict__ b2p, float* __restrict__ att,
                       float* __restrict__ iw)
{
  constexpr int PER = (L + 255) / 256;
  __shared__ float red[4];
  const int tid = threadIdx.x, b = blockIdx.x;
  const float b2v = b2p[0];
  float xs[PER];
  float mx = -__builtin_inff();
#pragma unroll
  for (int i = 0; i < PER; ++i) {
    int idx = tid + i * 256;
    if (idx < L) {
      float v = mask[(long)b * L + idx] ? NEGV : (logit[(long)b * L + idx] + b2v);
      xs[i] = v; mx = fmaxf(mx, v);
    } else xs[i] = -__builtin_inff();
  }
#pragma unroll
  for (int s = 32; s >= 1; s >>= 1) mx = fmaxf(mx, __shfl_xor(mx, s));
  if ((tid & 63) == 0) red[tid >> 6] = mx;
  __syncthreads();
  mx = fmaxf(fmaxf(red[0], red[1]), fmaxf(red[2], red[3]));
  __syncthreads();
  float sum = 0.f;
#pragma unroll
  for (int i = 0; i < PER; ++i) {
    int idx = tid + i * 256;
    if (idx < L) { xs[i] = __expf(xs[i] - mx); sum += xs[i]; }
  }
#pragma unroll
  for (int s = 32; s >= 1; s >>= 1) sum += __shfl_xor(sum, s);
  if ((tid & 63) == 0) red[tid >> 6] = sum;
  __syncthreads();
  sum = red[0] + red[1] + red[2] + red[3];
  const float inv = 1.f / sum;
#pragma unroll
  for (int i = 0; i < PER; ++i) {
    int idx = tid + i * 256;
    if (idx < L) {
      float a = xs[i] * inv;
      att[(long)b * L + idx] = a;
      if (iw) iw[(long)b * L + idx] = a;
    }
  }
}

// pooled[b,d] = sum_m att[b,m]*X[b,m,d]; 512 thr, ushort2 loads, 8-way m-split
template<int L>
__global__ void pooled_k(const float* __restrict__ att, const unsigned short* __restrict__ X,
                         float* __restrict__ out)
{
  __shared__ float a[L];
  __shared__ float2 part[8][64];
  const int b = blockIdx.x, tid = threadIdx.x;
  const int lane = tid & 63, grp = tid >> 6;
  const int d0 = blockIdx.y * 128 + lane * 2;
  for (int i = tid; i < L; i += 512) a[i] = att[(long)b * L + i];
  __syncthreads();
  const unsigned short* xb = X + (long)b * L * D + d0;
  float s0 = 0.f, s1 = 0.f;
  const int m0 = grp * (L / 8);
#pragma unroll 4
  for (int m = m0; m < m0 + L / 8; ++m) {
    ushort2 v = *(const ushort2*)&xb[(long)m * D];
    float av = a[m];
    s0 += av * bf2f(v.x); s1 += av * bf2f(v.y);
  }
  part[grp][lane] = make_float2(s0, s1);
  __syncthreads();
  if (tid < 64) {
    float r0 = 0.f, r1 = 0.f;
#pragma unroll
    for (int gi = 0; gi < 8; ++gi) { r0 += part[gi][tid].x; r1 += part[gi][tid].y; }
    *(float2*)&out[b * D + blockIdx.y * 128 + tid * 2] = make_float2(r0, r1);
  }
}

// out[b,n] += partial over k-slice of pooled[b,:]@W ; out pre-zeroed
__global__ void final_k(const float* __restrict__ pooled, const float* __restrict__ W,
                        const float* __restrict__ bias, float* __restrict__ out)
{
  __shared__ float p[160];
  const int b = blockIdx.x, tid = threadIdx.x;
  const int nn = blockIdx.y * 128 + tid;
  const int k0 = blockIdx.z * 160;
  for (int i = tid; i < 160; i += 128) p[i] = pooled[b * D + k0 + i];
  __syncthreads();
  float acc = (blockIdx.z == 0) ? bias[nn] : 0.f;
  for (int k = 0; k < 160; ++k) acc += p[k] * W[(long)(k0 + k) * D + nn];
  atomicAdd(&out[b * D + nn], acc);
}

// 64x64 tile cast: read f32 once (float4), emit row-major bf16 (opt) + transposed bf16
template<int WRITE_N>
__global__ void cast_t_k(const float* __restrict__ in, unsigned short* __restrict__ outN,
                         unsigned short* __restrict__ outT, int R, int C)
{
  __shared__ float t[64][65];
  const int tid = threadIdx.x;
  const int cg = tid & 15, rw = tid >> 4;
  const long base = (long)blockIdx.z * R * C;
  const int c0 = blockIdx.x * 64, r0 = blockIdx.y * 64;
#pragma unroll
  for (int p = 0; p < 4; ++p) {
    int row = p * 16 + rw;
    float4 v = *(const float4*)&in[base + (long)(r0 + row) * C + c0 + cg * 4];
    *(float4*)&t[row][cg * 4] = v;
    if (WRITE_N) {
      ushort4 o;
      o.x = f2bf(v.x); o.y = f2bf(v.y); o.z = f2bf(v.z); o.w = f2bf(v.w);
      *(ushort4*)&outN[base + (long)(r0 + row) * C + c0 + cg * 4] = o;
    }
  }
  __syncthreads();
#pragma unroll
  for (int p = 0; p < 4; ++p) {
    int ocol = p * 16 + rw;
    ushort4 o;
    o.x = f2bf(t[cg * 4 + 0][ocol]);
    o.y = f2bf(t[cg * 4 + 1][ocol]);
    o.z = f2bf(t[cg * 4 + 2][ocol]);
    o.w = f2bf(t[cg * 4 + 3][ocol]);
    *(ushort4*)&outT[base + (long)(c0 + ocol) * R + r0 + cg * 4] = o;
  }
}

extern "C" void kernel_launch(void* const* d_in, const int* in_sizes, int n_in,
                              void* d_out, int out_size, void* d_ws, size_t ws_size,
                              hipStream_t stream)
{
  (void)in_sizes; (void)n_in; (void)out_size; (void)ws_size;
  const float* i_batch = (const float*)d_in[0];
  const float* q_batch = (const float*)d_in[1];
  const int*   i_mask  = (const int*)d_in[2];
  const int*   q_mask  = (const int*)d_in[3];
  const float* lW1 = (const float*)d_in[4];
  const float* lb1 = (const float*)d_in[5];
  const float* lW2 = (const float*)d_in[6];
  const float* lb2 = (const float*)d_in[7];
  const float* lWm = (const float*)d_in[8];
  const float* lbm = (const float*)d_in[9];
  const float* iW1 = (const float*)d_in[10];
  const float* ib1 = (const float*)d_in[11];
  const float* iW2 = (const float*)d_in[12];
  const float* ib2 = (const float*)d_in[13];
  const float* iWm = (const float*)d_in[14];
  const float* ibm = (const float*)d_in[15];
  float* out_if = (float*)d_out;          // (64,640)
  float* out_lf = out_if + B * D;         // (64,640)
  float* out_iw = out_lf + B * D;         // (64,512)

  char* wp = (char*)d_ws;
  size_t off = 0;
  auto alloc = [&](size_t bytes) { void* p = wp + off; off += (bytes + 255) & ~(size_t)255; return p; };
  unsigned short* i_bf   = (unsigned short*)alloc((size_t)B * NI * D * 2);
  unsigned short* i_bfT  = (unsigned short*)alloc((size_t)B * NI * D * 2);
  unsigned short* q_bf   = (unsigned short*)alloc((size_t)B * NQ * D * 2);
  unsigned short* q_bfT  = (unsigned short*)alloc((size_t)B * NQ * D * 2);
  unsigned short* x1_bf  = (unsigned short*)alloc((size_t)B * NI * D * 2);
  unsigned short* x2_bf  = (unsigned short*)alloc((size_t)B * NQ * D * 2);
  float*          scores = (float*)alloc((size_t)B * NQ * NI * 4);          // dir2 only
  unsigned short* p_bf   = (unsigned short*)alloc((size_t)B * NI * NQ * 2); // shared both dirs
  unsigned short* lW1t   = (unsigned short*)alloc((size_t)H * D * 2);
  unsigned short* iW1t   = (unsigned short*)alloc((size_t)H * D * 2);
  float* logit1  = (float*)alloc((size_t)B * NI * 4);
  float* att1    = (float*)alloc((size_t)B * NI * 4);
  float* logit2  = (float*)alloc((size_t)B * NQ * 4);
  float* att2    = (float*)alloc((size_t)B * NQ * 4);
  float* pooled1 = (float*)alloc((size_t)B * D * 4);
  float* pooled2 = (float*)alloc((size_t)B * D * 4);

  // zero atomic-accumulated buffers (logit1..att2 contiguous)
  hipMemsetAsync(out_if, 0, (size_t)2 * B * D * 4, stream);
  hipMemsetAsync(logit1, 0, (size_t)(B * NI * 2 + B * NQ * 2) * 4, stream);

  // ---- prep: fused cast+transpose (read inputs once, vectorized) ----
  cast_t_k<1><<<dim3(D / 64, NI / 64, B), 256, 0, stream>>>(i_batch, i_bf, i_bfT, NI, D);
  cast_t_k<1><<<dim3(D / 64, NQ / 64, B), 256, 0, stream>>>(q_batch, q_bf, q_bfT, NQ, D);
  cast_t_k<0><<<dim3(H / 64, D / 64, 1), 256, 0, stream>>>(lW1, nullptr, lW1t, D, H);
  cast_t_k<0><<<dim3(H / 64, D / 64, 1), 256, 0, stream>>>(iW1, nullptr, iW1t, D, H);

  // ---- direction 1: i_feat = attn(i_batch -> q_batch), attflat(lW*) ----
  qksm_k<<<dim3(4 * B), 256, 0, stream>>>(i_bf, q_bf, q_mask, p_bf);
  gemm_nt<1><<<dim3((NI / 128) * (D / 128) * B), 256, 0, stream>>>(
      p_bf, q_bfT, x1_bf, NQ, NQ, D, NQ, (long)NI * NQ, (long)D * NQ, (long)NI * D,
      NI / 128, D / 128);
  hatt_k<<<dim3((H / 128) * (B * NI / 128)), 256, 0, stream>>>(x1_bf, lW1t, lb1, lW2, logit1);
  sm_att<NI><<<dim3(B), 256, 0, stream>>>(logit1, i_mask, lb2, att1, out_iw);
  pooled_k<NI><<<dim3(B, D / 128), 512, 0, stream>>>(att1, x1_bf, pooled1);
  final_k<<<dim3(B, D / 128, 4), 128, 0, stream>>>(pooled1, lWm, lbm, out_if);

  // ---- direction 2: l_feat = attn(q_batch -> i_batch), attflat(iW*) ----
  gemm_nt<0><<<dim3((NQ / 128) * (NI / 128) * B), 256, 0, stream>>>(
      q_bf, i_bf, scores, D, D, NI, D, (long)NQ * D, (long)NI * D, (long)NQ * NI,
      NQ / 128, NI / 128);
  sm_scores<NI><<<dim3(B * NQ / 4), 256, 0, stream>>>(scores, i_mask, p_bf, NQ);
  gemm_nt<1><<<dim3((NQ / 128) * (D / 128) * B), 256, 0, stream>>>(
      p_bf, i_bfT, x2_bf, NI, NI, D, NI, (long)NQ * NI, (long)D * NI, (long)NQ * D,
      NQ / 128, D / 128);
  hatt_k<<<dim3((H / 128) * (B * NQ / 128)), 256, 0, stream>>>(x2_bf, iW1t, ib1, iW2, logit2);
  sm_att<NQ><<<dim3(B), 256, 0, stream>>>(logit2, q_mask, ib2, att2, nullptr);
  pooled_k<NQ><<<dim3(B, D / 128), 512, 0, stream>>>(att2, x2_bf, pooled2);
  final_k<<<dim3(B, D / 128, 4), 128, 0, stream>>>(pooled2, iWm, ibm, out_lf);
}

// Round 4
// 427.333 us; speedup vs baseline: 1.1648x; 1.0011x over previous
//
#include <hip/hip_runtime.h>
#include <cstdint>

#define DEV __device__ __forceinline__

typedef __attribute__((ext_vector_type(8))) short bf16x8;
typedef __attribute__((ext_vector_type(4))) float f32x4;

static constexpr int B  = 64;
static constexpr int NI = 512;
static constexpr int NQ = 128;
static constexpr int D  = 640;
static constexpr int H  = 1280;
static constexpr float NEGV  = -65504.0f;
static constexpr float SCALE = 0.039528470752104745f; // 1/sqrt(640)

DEV unsigned short f2bf(float f) {
  union { float f; uint32_t u; } c; c.f = f;
  uint32_t u = c.u;
  u += 0x7fffu + ((u >> 16) & 1u);     // RTNE
  return (unsigned short)(u >> 16);
}
DEV float bf2f(unsigned short h) {
  union { uint32_t u; float f; } c; c.u = ((uint32_t)h) << 16;
  return c.f;
}

// XCD-chunked bijective swizzle (nwg must be %8==0)
DEV int xcd_swz(int bid, int nwg) {
  return (bid & 7) * (nwg >> 3) + (bid >> 3);
}

// async global->LDS, 16B per lane
DEV void gll16(const void* g, void* l) {
  __builtin_amdgcn_global_load_lds(
      (const __attribute__((address_space(1))) void*)(uintptr_t)g,
      (__attribute__((address_space(3))) void*)(uint32_t)(uintptr_t)l,
      16, 0, 0);
}

// stage a ROWS x 64-col bf16 tile into LDS, XOR-swizzled source columns
// LDS[row][c] = G[row][c ^ (row&7)]  (c = 16B chunk 0..7 within row)
template<int ROWS>
DEV void stageT(const unsigned short* src, int ld, unsigned short* lds, int tid) {
  const int w = tid >> 6, lane = tid & 63;
#pragma unroll
  for (int i = 0; i < ROWS / 32; ++i) {
    int c = w * (ROWS * 2) + i * 64 + lane;
    int r = c >> 3, ck = c & 7;
    int col8 = ((ck ^ (r & 7)) << 3);
    gll16(src + (long)r * ld + col8, (char*)lds + (size_t)c * 16);
  }
}

// swizzled fragment read for 64-col rows
DEV bf16x8 frag(const unsigned short* ls, int row, int q) {
  return *(const bf16x8*)&ls[row * 64 + ((q ^ (row & 7)) << 3)];
}
// swizzled fragment read for 128-col rows (16 chunks)
DEV bf16x8 fragP(const unsigned short* P, int row, int q) {
  return *(const bf16x8*)&P[row * 128 + ((q ^ (row & 7)) << 3)];
}

// C(M,N) = A(M,K) @ Bt(N,K)^T; bf16 in, fp32 acc; BK=64, depth-1 prefetch dbuf
template<int OUT_BF16>
__global__ __launch_bounds__(256, 2) void gemm_nt(
    const unsigned short* __restrict__ A, const unsigned short* __restrict__ Bt,
    void* __restrict__ C, int lda, int ldb, int ldc, int K,
    long sA, long sB, long sC, int gx, int gy)
{
  __shared__ __align__(16) unsigned short lsA[2][128 * 64];
  __shared__ __align__(16) unsigned short lsB[2][128 * 64];
  const int tid = threadIdx.x;
  const int w = tid >> 6, lane = tid & 63;
  const int wm = w >> 1, wn = w & 1;
  const int g = lane >> 4, r = lane & 15;
  const int wg = xcd_swz(blockIdx.x, gridDim.x);
  const int bz = wg / (gx * gy);
  const int r2 = wg - bz * gx * gy;
  const int by = r2 / gx;
  const int bx = r2 - by * gx;
  const long zb = bz;
  const unsigned short* Ab = A + zb * sA + (long)bx * 128 * lda;
  const unsigned short* Bb = Bt + zb * sB + (long)by * 128 * ldb;

  const int nt = K >> 6;
  stageT<128>(Ab, lda, lsA[0], tid);
  stageT<128>(Bb, ldb, lsB[0], tid);
  f32x4 acc[4][4] = {};
  for (int t = 0; t < nt; ++t) {
    __syncthreads();                       // tile t staged; prev reads done
    if (t + 1 < nt) {
      stageT<128>(Ab + (t + 1) * 64, lda, lsA[(t + 1) & 1], tid);
      stageT<128>(Bb + (t + 1) * 64, ldb, lsB[(t + 1) & 1], tid);
    }
    const unsigned short* la = lsA[t & 1];
    const unsigned short* lb = lsB[t & 1];
#pragma unroll
    for (int kk = 0; kk < 2; ++kk) {
      bf16x8 af[4], bfr[4];
#pragma unroll
      for (int mi = 0; mi < 4; ++mi) af[mi]  = frag(la, wm * 64 + mi * 16 + r, kk * 4 + g);
#pragma unroll
      for (int ni = 0; ni < 4; ++ni) bfr[ni] = frag(lb, wn * 64 + ni * 16 + r, kk * 4 + g);
#pragma unroll
      for (int mi = 0; mi < 4; ++mi)
#pragma unroll
        for (int ni = 0; ni < 4; ++ni)
          acc[mi][ni] = __builtin_amdgcn_mfma_f32_16x16x32_bf16(af[mi], bfr[ni], acc[mi][ni], 0, 0, 0);
    }
  }
  const int row0 = bx * 128 + wm * 64;
  const int col0 = by * 128 + wn * 64;
#pragma unroll
  for (int mi = 0; mi < 4; ++mi)
#pragma unroll
    for (int ni = 0; ni < 4; ++ni)
#pragma unroll
      for (int j = 0; j < 4; ++j) {
        int rr = row0 + mi * 16 + g * 4 + j;
        int cc = col0 + ni * 16 + r;
        float v = acc[mi][ni][j];
        if (OUT_BF16)
          ((unsigned short*)C)[zb * sC + (long)rr * ldc + cc] = f2bf(v);
        else
          ((float*)C)[zb * sC + (long)rr * ldc + cc] = v;
      }
}

// fused dir-1 attention: x1-tile = softmax(mask(Q@K^T*SCALE)) @ V
// 64-row Q tiles; K/V = q_batch (128 x 640). P kept in LDS, never global.
__global__ __launch_bounds__(256, 2) void fattn1_k(
    const unsigned short* __restrict__ Qm,   // i_bf  (B,NI,D)
    const unsigned short* __restrict__ Km,   // q_bf  (B,NQ,D)
    const unsigned short* __restrict__ Vt,   // q_bfT (B,D,NQ)
    const int* __restrict__ mask,            // (B,NQ)
    unsigned short* __restrict__ O)          // x1 (B,NI,D)
{
  __shared__ __align__(16) unsigned short sh[64 * 64 + 128 * 64]; // 24KB: Q|K, later P(16KB)
  __shared__ __align__(16) unsigned short lsV[2][128 * 64];       // 32KB: V k-halves
  __shared__ float red0[64][2], red1[64][2];
  unsigned short* lsQ = sh;
  unsigned short* lsK = sh + 64 * 64;
  unsigned short* Pl  = sh;                  // aliases Q|K after QK phase
  const int tid = threadIdx.x;
  const int w = tid >> 6, lane = tid & 63;
  const int wm = w >> 1, wn = w & 1;
  const int g = lane >> 4, r = lane & 15;
  const int wg = xcd_swz(blockIdx.x, gridDim.x);
  const int mt = wg & 7, b = wg >> 3;
  const unsigned short* Qb = Qm + ((long)b * NI + (long)mt * 64) * D;
  const unsigned short* Kb = Km + (long)b * NQ * D;
  const unsigned short* Vb = Vt + (long)b * D * NQ;

  int mki[4];
#pragma unroll
  for (int ni = 0; ni < 4; ++ni) mki[ni] = mask[b * NQ + wn * 64 + ni * 16 + r];

  // ---- QK^T ----
  f32x4 acc[2][4] = {};
  for (int k0 = 0; k0 < D; k0 += 64) {
    stageT<64>(Qb + k0, D, lsQ, tid);
    stageT<128>(Kb + k0, D, lsK, tid);
    __syncthreads();
#pragma unroll
    for (int kk = 0; kk < 2; ++kk) {
      bf16x8 af[2], bfr[4];
#pragma unroll
      for (int mi = 0; mi < 2; ++mi) af[mi]  = frag(lsQ, wm * 32 + mi * 16 + r, kk * 4 + g);
#pragma unroll
      for (int ni = 0; ni < 4; ++ni) bfr[ni] = frag(lsK, wn * 64 + ni * 16 + r, kk * 4 + g);
#pragma unroll
      for (int mi = 0; mi < 2; ++mi)
#pragma unroll
        for (int ni = 0; ni < 4; ++ni)
          acc[mi][ni] = __builtin_amdgcn_mfma_f32_16x16x32_bf16(af[mi], bfr[ni], acc[mi][ni], 0, 0, 0);
    }
    __syncthreads();
  }

  // ---- masked softmax (wave-parallel, 16-lane-group reduce over cols) ----
  float x[2][4][4], pm[2][4];
#pragma unroll
  for (int mi = 0; mi < 2; ++mi)
#pragma unroll
    for (int j = 0; j < 4; ++j) pm[mi][j] = -3.4e38f;
#pragma unroll
  for (int mi = 0; mi < 2; ++mi)
#pragma unroll
    for (int ni = 0; ni < 4; ++ni)
#pragma unroll
      for (int j = 0; j < 4; ++j) {
        float v = mki[ni] ? NEGV : acc[mi][ni][j] * SCALE;
        x[mi][ni][j] = v;
        pm[mi][j] = fmaxf(pm[mi][j], v);
      }
#pragma unroll
  for (int s = 1; s < 16; s <<= 1)
#pragma unroll
    for (int mi = 0; mi < 2; ++mi)
#pragma unroll
      for (int j = 0; j < 4; ++j) pm[mi][j] = fmaxf(pm[mi][j], __shfl_xor(pm[mi][j], s));
  if (r == 0) {
#pragma unroll
    for (int mi = 0; mi < 2; ++mi)
#pragma unroll
      for (int j = 0; j < 4; ++j) red0[wm * 32 + mi * 16 + g * 4 + j][wn] = pm[mi][j];
  }
  __syncthreads();
  float mx[2][4], ps[2][4];
#pragma unroll
  for (int mi = 0; mi < 2; ++mi)
#pragma unroll
    for (int j = 0; j < 4; ++j) {
      int rl = wm * 32 + mi * 16 + g * 4 + j;
      mx[mi][j] = fmaxf(red0[rl][0], red0[rl][1]);
      ps[mi][j] = 0.f;
    }
#pragma unroll
  for (int mi = 0; mi < 2; ++mi)
#pragma unroll
    for (int ni = 0; ni < 4; ++ni)
#pragma unroll
      for (int j = 0; j < 4; ++j) {
        float e = __expf(x[mi][ni][j] - mx[mi][j]);
        x[mi][ni][j] = e;
        ps[mi][j] += e;
      }
#pragma unroll
  for (int s = 1; s < 16; s <<= 1)
#pragma unroll
    for (int mi = 0; mi < 2; ++mi)
#pragma unroll
      for (int j = 0; j < 4; ++j) ps[mi][j] += __shfl_xor(ps[mi][j], s);
  if (r == 0) {
#pragma unroll
    for (int mi = 0; mi < 2; ++mi)
#pragma unroll
      for (int j = 0; j < 4; ++j) red1[wm * 32 + mi * 16 + g * 4 + j][wn] = ps[mi][j];
  }
  __syncthreads();
  // write P (bf16, chunk-swizzled) into LDS; stage V chunk 0 meanwhile
#pragma unroll
  for (int mi = 0; mi < 2; ++mi)
#pragma unroll
    for (int j = 0; j < 4; ++j) {
      int rl = wm * 32 + mi * 16 + g * 4 + j;
      float inv = 1.f / (red1[rl][0] + red1[rl][1]);
#pragma unroll
      for (int ni = 0; ni < 4; ++ni) {
        int col = wn * 64 + ni * 16 + r;
        Pl[rl * 128 + (((col >> 3) ^ (rl & 7)) << 3) + (col & 7)] = f2bf(x[mi][ni][j] * inv);
      }
    }
  stageT<128>(Vb, 128, lsV[0], tid);
  stageT<128>(Vb + 64, 128, lsV[1], tid);
  __syncthreads();   // P + V(0) ready

  // ---- PV: 5 d-chunks of 128 ----
  for (int nc = 0; nc < 5; ++nc) {
    if (nc > 0) __syncthreads();           // V(nc) staged
    f32x4 po[2][4] = {};
#pragma unroll
    for (int kk2 = 0; kk2 < 2; ++kk2)
#pragma unroll
      for (int kk = 0; kk < 2; ++kk) {
        bf16x8 af[2], bfr[4];
#pragma unroll
        for (int mi = 0; mi < 2; ++mi) af[mi]  = fragP(Pl, wm * 32 + mi * 16 + r, kk2 * 8 + kk * 4 + g);
#pragma unroll
        for (int ni = 0; ni < 4; ++ni) bfr[ni] = frag(lsV[kk2], wn * 64 + ni * 16 + r, kk * 4 + g);
#pragma unroll
        for (int mi = 0; mi < 2; ++mi)
#pragma unroll
          for (int ni = 0; ni < 4; ++ni)
            po[mi][ni] = __builtin_amdgcn_mfma_f32_16x16x32_bf16(af[mi], bfr[ni], po[mi][ni], 0, 0, 0);
      }
    __syncthreads();                       // all waves done reading lsV
    if (nc < 4) {
      const unsigned short* Vn = Vb + (long)(nc + 1) * 128 * 128;
      stageT<128>(Vn, 128, lsV[0], tid);
      stageT<128>(Vn + 64, 128, lsV[1], tid);
    }
#pragma unroll
    for (int mi = 0; mi < 2; ++mi)
#pragma unroll
      for (int ni = 0; ni < 4; ++ni)
#pragma unroll
        for (int j = 0; j < 4; ++j) {
          int rr = mt * 64 + wm * 32 + mi * 16 + g * 4 + j;
          int cc = nc * 128 + wn * 64 + ni * 16 + r;
          O[((long)b * NI + rr) * D + cc] = f2bf(po[mi][ni][j]);
        }
  }
}

// fused attflat MLP: logit[m] += sum_n relu(A@W1t^T + b1)[m,n] * W2[n]
__global__ __launch_bounds__(256, 2) void hatt_k(
    const unsigned short* __restrict__ A, const unsigned short* __restrict__ Bt,
    const float* __restrict__ b1, const float* __restrict__ W2,
    float* __restrict__ outlogit)
{
  constexpr int NH = H / 128;
  __shared__ __align__(16) unsigned short lsA[2][128 * 64];
  __shared__ __align__(16) unsigned short lsB[2][128 * 64];
  __shared__ float b1c[128], w2c[128];
  const int tid = threadIdx.x;
  const int w = tid >> 6, lane = tid & 63;
  const int wm = w >> 1, wn = w & 1;
  const int g = lane >> 4, r = lane & 15;
  const int wg = xcd_swz(blockIdx.x, gridDim.x);
  const int n0 = (wg % NH) * 128;
  const int m0 = (wg / NH) * 128;
  if (tid < 128) { b1c[tid] = b1[n0 + tid]; w2c[tid] = W2[n0 + tid]; }
  const unsigned short* Ab = A + (long)m0 * D;
  const unsigned short* Bb = Bt + (long)n0 * D;

  constexpr int NT = D / 64;
  stageT<128>(Ab, D, lsA[0], tid);
  stageT<128>(Bb, D, lsB[0], tid);
  f32x4 acc[4][4] = {};
  for (int t = 0; t < NT; ++t) {
    __syncthreads();
    if (t + 1 < NT) {
      stageT<128>(Ab + (t + 1) * 64, D, lsA[(t + 1) & 1], tid);
      stageT<128>(Bb + (t + 1) * 64, D, lsB[(t + 1) & 1], tid);
    }
    const unsigned short* la = lsA[t & 1];
    const unsigned short* lb = lsB[t & 1];
#pragma unroll
    for (int kk = 0; kk < 2; ++kk) {
      bf16x8 af[4], bfr[4];
#pragma unroll
      for (int mi = 0; mi < 4; ++mi) af[mi]  = frag(la, wm * 64 + mi * 16 + r, kk * 4 + g);
#pragma unroll
      for (int ni = 0; ni < 4; ++ni) bfr[ni] = frag(lb, wn * 64 + ni * 16 + r, kk * 4 + g);
#pragma unroll
      for (int mi = 0; mi < 4; ++mi)
#pragma unroll
        for (int ni = 0; ni < 4; ++ni)
          acc[mi][ni] = __builtin_amdgcn_mfma_f32_16x16x32_bf16(af[mi], bfr[ni], acc[mi][ni], 0, 0, 0);
    }
  }
  float rs[4][4];
#pragma unroll
  for (int mi = 0; mi < 4; ++mi)
#pragma unroll
    for (int j = 0; j < 4; ++j) rs[mi][j] = 0.f;
#pragma unroll
  for (int mi = 0; mi < 4; ++mi)
#pragma unroll
    for (int ni = 0; ni < 4; ++ni)
#pragma unroll
      for (int j = 0; j < 4; ++j) {
        int cl = wn * 64 + ni * 16 + r;
        float h = acc[mi][ni][j] + b1c[cl];
        h = fmaxf(h, 0.f);
        rs[mi][j] += h * w2c[cl];
      }
#pragma unroll
  for (int mi = 0; mi < 4; ++mi)
#pragma unroll
    for (int j = 0; j < 4; ++j) {
      float v = rs[mi][j];
      v += __shfl_xor(v, 1); v += __shfl_xor(v, 2);
      v += __shfl_xor(v, 4); v += __shfl_xor(v, 8);
      if (r == 0) atomicAdd(&outlogit[m0 + wm * 64 + mi * 16 + g * 4 + j], v);
    }
}

// masked row softmax over fp32 scores (one wave per row), writes bf16 P (dir 2)
template<int L>
__global__ void sm_scores(const float* __restrict__ S, const int* __restrict__ mask,
                          unsigned short* __restrict__ P, int M)
{
  constexpr int NV = L / 64;
  const int wid = threadIdx.x >> 6, lane = threadIdx.x & 63;
  const long row = (long)blockIdx.x * 4 + wid;
  const int b = (int)(row / M);
  const float* s = S + row * (long)L;
  const int* mk = mask + (long)b * L;
  float x[NV];
  float mx = -__builtin_inff();
#pragma unroll
  for (int i = 0; i < NV; ++i) {
    int idx = i * 64 + lane;
    float v = s[idx] * SCALE;
    x[i] = mk[idx] ? NEGV : v;
    mx = fmaxf(mx, x[i]);
  }
#pragma unroll
  for (int sft = 32; sft >= 1; sft >>= 1) mx = fmaxf(mx, __shfl_xor(mx, sft));
  float sum = 0.f;
#pragma unroll
  for (int i = 0; i < NV; ++i) { x[i] = __expf(x[i] - mx); sum += x[i]; }
#pragma unroll
  for (int sft = 32; sft >= 1; sft >>= 1) sum += __shfl_xor(sum, sft);
  const float inv = 1.f / sum;
  unsigned short* p = P + row * (long)L;
#pragma unroll
  for (int i = 0; i < NV; ++i) p[i * 64 + lane] = f2bf(x[i] * inv);
}

// fused tail: softmax(logit,mask)+b2 -> att; pooled = att@X; out = pooled@Wm + bm
template<int L>
__global__ __launch_bounds__(640, 1) void tail_k(
    const float* __restrict__ logit, const int* __restrict__ mask,
    const float* __restrict__ b2p, const unsigned short* __restrict__ X,
    const float* __restrict__ Wm, const float* __restrict__ bm,
    float* __restrict__ outF, float* __restrict__ iw)
{
  __shared__ float att[L];
  __shared__ float pool[D];
  __shared__ float red[10];
  const int tid = threadIdx.x, b = blockIdx.x;
  const int lane = tid & 63, wv = tid >> 6;
  const float b2v = b2p[0];
  float v = -__builtin_inff();
  if (tid < L) v = mask[(long)b * L + tid] ? NEGV : (logit[(long)b * L + tid] + b2v);
  float m = v;
#pragma unroll
  for (int s = 32; s >= 1; s >>= 1) m = fmaxf(m, __shfl_xor(m, s));
  if (lane == 0) red[wv] = m;
  __syncthreads();
  float mx = red[0];
#pragma unroll
  for (int i = 1; i < 10; ++i) mx = fmaxf(mx, red[i]);
  __syncthreads();
  float e = (tid < L) ? __expf(v - mx) : 0.f;
  float ssum = e;
#pragma unroll
  for (int s = 32; s >= 1; s >>= 1) ssum += __shfl_xor(ssum, s);
  if (lane == 0) red[wv] = ssum;
  __syncthreads();
  float tot = 0.f;
#pragma unroll
  for (int i = 0; i < 10; ++i) tot += red[i];
  const float a = e / tot;
  if (tid < L) { att[tid] = a; if (iw) iw[(long)b * L + tid] = a; }
  __syncthreads();
  // pooled[d] = sum_m att[m] * X[b,m,d]   (thread = d)
  const unsigned short* Xb = X + (long)b * L * D + tid;
  float s = 0.f;
  for (int m2 = 0; m2 < L; ++m2) s += att[m2] * bf2f(Xb[(long)m2 * D]);
  pool[tid] = s;
  __syncthreads();
  // out[n] = bm[n] + sum_k pool[k] * Wm[k,n]   (thread = n)
  float o = bm[tid];
  for (int k = 0; k < D; ++k) o += pool[k] * Wm[(long)k * D + tid];
  outF[(long)b * D + tid] = o;
}

// 64x64 tile cast: read f32 once (float4), emit row-major bf16 (opt) + transposed bf16
template<int WRITE_N>
__global__ void cast_t_k(const float* __restrict__ in, unsigned short* __restrict__ outN,
                         unsigned short* __restrict__ outT, int R, int C)
{
  __shared__ float t[64][65];
  const int tid = threadIdx.x;
  const int cg = tid & 15, rw = tid >> 4;
  const long base = (long)blockIdx.z * R * C;
  const int c0 = blockIdx.x * 64, r0 = blockIdx.y * 64;
#pragma unroll
  for (int p = 0; p < 4; ++p) {
    int row = p * 16 + rw;
    float4 v = *(const float4*)&in[base + (long)(r0 + row) * C + c0 + cg * 4];
    *(float4*)&t[row][cg * 4] = v;
    if (WRITE_N) {
      ushort4 o;
      o.x = f2bf(v.x); o.y = f2bf(v.y); o.z = f2bf(v.z); o.w = f2bf(v.w);
      *(ushort4*)&outN[base + (long)(r0 + row) * C + c0 + cg * 4] = o;
    }
  }
  __syncthreads();
#pragma unroll
  for (int p = 0; p < 4; ++p) {
    int ocol = p * 16 + rw;
    ushort4 o;
    o.x = f2bf(t[cg * 4 + 0][ocol]);
    o.y = f2bf(t[cg * 4 + 1][ocol]);
    o.z = f2bf(t[cg * 4 + 2][ocol]);
    o.w = f2bf(t[cg * 4 + 3][ocol]);
    *(ushort4*)&outT[base + (long)(c0 + ocol) * R + r0 + cg * 4] = o;
  }
}

extern "C" void kernel_launch(void* const* d_in, const int* in_sizes, int n_in,
                              void* d_out, int out_size, void* d_ws, size_t ws_size,
                              hipStream_t stream)
{
  (void)in_sizes; (void)n_in; (void)out_size; (void)ws_size;
  const float* i_batch = (const float*)d_in[0];
  const float* q_batch = (const float*)d_in[1];
  const int*   i_mask  = (const int*)d_in[2];
  const int*   q_mask  = (const int*)d_in[3];
  const float* lW1 = (const float*)d_in[4];
  const float* lb1 = (const float*)d_in[5];
  const float* lW2 = (const float*)d_in[6];
  const float* lb2 = (const float*)d_in[7];
  const float* lWm = (const float*)d_in[8];
  const float* lbm = (const float*)d_in[9];
  const float* iW1 = (const float*)d_in[10];
  const float* ib1 = (const float*)d_in[11];
  const float* iW2 = (const float*)d_in[12];
  const float* ib2 = (const float*)d_in[13];
  const float* iWm = (const float*)d_in[14];
  const float* ibm = (const float*)d_in[15];
  float* out_if = (float*)d_out;          // (64,640)
  float* out_lf = out_if + B * D;         // (64,640)
  float* out_iw = out_lf + B * D;         // (64,512)

  char* wp = (char*)d_ws;
  size_t off = 0;
  auto alloc = [&](size_t bytes) { void* p = wp + off; off += (bytes + 255) & ~(size_t)255; return p; };
  unsigned short* i_bf   = (unsigned short*)alloc((size_t)B * NI * D * 2);
  unsigned short* i_bfT  = (unsigned short*)alloc((size_t)B * NI * D * 2);
  unsigned short* q_bf   = (unsigned short*)alloc((size_t)B * NQ * D * 2);
  unsigned short* q_bfT  = (unsigned short*)alloc((size_t)B * NQ * D * 2);
  unsigned short* x1_bf  = (unsigned short*)alloc((size_t)B * NI * D * 2);
  unsigned short* x2_bf  = (unsigned short*)alloc((size_t)B * NQ * D * 2);
  float*          scores = (float*)alloc((size_t)B * NQ * NI * 4);          // dir2 only
  unsigned short* p_bf   = (unsigned short*)alloc((size_t)B * NQ * NI * 2); // dir2 only
  unsigned short* lW1t   = (unsigned short*)alloc((size_t)H * D * 2);
  unsigned short* iW1t   = (unsigned short*)alloc((size_t)H * D * 2);
  float* logit1 = (float*)alloc((size_t)B * NI * 4);
  float* logit2 = (float*)alloc((size_t)B * NQ * 4);

  // zero the atomic-accumulated logits (contiguous allocs)
  hipMemsetAsync(logit1, 0, (size_t)(B * NI + B * NQ) * 4, stream);

  // ---- prep: fused cast+transpose (read inputs once, vectorized) ----
  cast_t_k<1><<<dim3(D / 64, NI / 64, B), 256, 0, stream>>>(i_batch, i_bf, i_bfT, NI, D);
  cast_t_k<1><<<dim3(D / 64, NQ / 64, B), 256, 0, stream>>>(q_batch, q_bf, q_bfT, NQ, D);
  cast_t_k<0><<<dim3(H / 64, D / 64, 1), 256, 0, stream>>>(lW1, nullptr, lW1t, D, H);
  cast_t_k<0><<<dim3(H / 64, D / 64, 1), 256, 0, stream>>>(iW1, nullptr, iW1t, D, H);

  // ---- direction 1 ----
  fattn1_k<<<dim3(8 * B), 256, 0, stream>>>(i_bf, q_bf, q_bfT, q_mask, x1_bf);
  hatt_k<<<dim3((H / 128) * (B * NI / 128)), 256, 0, stream>>>(x1_bf, lW1t, lb1, lW2, logit1);
  tail_k<NI><<<dim3(B), 640, 0, stream>>>(logit1, i_mask, lb2, x1_bf, lWm, lbm, out_if, out_iw);

  // ---- direction 2 ----
  gemm_nt<0><<<dim3((NQ / 128) * (NI / 128) * B), 256, 0, stream>>>(
      q_bf, i_bf, scores, D, D, NI, D, (long)NQ * D, (long)NI * D, (long)NQ * NI,
      NQ / 128, NI / 128);
  sm_scores<NI><<<dim3(B * NQ / 4), 256, 0, stream>>>(scores, i_mask, p_bf, NQ);
  gemm_nt<1><<<dim3((NQ / 128) * (D / 128) * B), 256, 0, stream>>>(
      p_bf, i_bfT, x2_bf, NI, NI, D, NI, (long)NQ * NI, (long)D * NI, (long)NQ * D,
      NQ / 128, D / 128);
  hatt_k<<<dim3((H / 128) * (B * NQ / 128)), 256, 0, stream>>>(x2_bf, iW1t, ib1, iW2, logit2);
  tail_k<NQ><<<dim3(B), 640, 0, stream>>>(logit2, q_mask, ib2, x2_bf, iWm, ibm, out_lf, nullptr);
}

// Round 5
// 419.034 us; speedup vs baseline: 1.1879x; 1.0198x over previous
//
#include <hip/hip_runtime.h>
#include <cstdint>

#define DEV __device__ __forceinline__

typedef __attribute__((ext_vector_type(8))) short bf16x8;
typedef __attribute__((ext_vector_type(4))) float f32x4;

static constexpr int B  = 64;
static constexpr int NI = 512;
static constexpr int NQ = 128;
static constexpr int D  = 640;
static constexpr int H  = 1280;
static constexpr float NEGV  = -65504.0f;
static constexpr float SCALE = 0.039528470752104745f; // 1/sqrt(640)

DEV unsigned short f2bf(float f) {
  union { float f; uint32_t u; } c; c.f = f;
  uint32_t u = c.u;
  u += 0x7fffu + ((u >> 16) & 1u);     // RTNE
  return (unsigned short)(u >> 16);
}
DEV float bf2f(unsigned short h) {
  union { uint32_t u; float f; } c; c.u = ((uint32_t)h) << 16;
  return c.f;
}

// XCD-chunked bijective swizzle (nwg must be %8==0)
DEV int xcd_swz(int bid, int nwg) {
  return (bid & 7) * (nwg >> 3) + (bid >> 3);
}

// async global->LDS, 16B per lane
DEV void gll16(const void* g, void* l) {
  __builtin_amdgcn_global_load_lds(
      (const __attribute__((address_space(1))) void*)(uintptr_t)g,
      (__attribute__((address_space(3))) void*)(uint32_t)(uintptr_t)l,
      16, 0, 0);
}

// ---- BK=64 staging (used by fattn1 only) ----
template<int ROWS>
DEV void stageT(const unsigned short* src, int ld, unsigned short* lds, int tid) {
  const int w = tid >> 6, lane = tid & 63;
#pragma unroll
  for (int i = 0; i < ROWS / 32; ++i) {
    int c = w * (ROWS * 2) + i * 64 + lane;
    int r = c >> 3, ck = c & 7;
    int col8 = ((ck ^ (r & 7)) << 3);
    gll16(src + (long)r * ld + col8, (char*)lds + (size_t)c * 16);
  }
}
DEV bf16x8 frag(const unsigned short* ls, int row, int q) {
  return *(const bf16x8*)&ls[row * 64 + ((q ^ (row & 7)) << 3)];
}
DEV bf16x8 fragP(const unsigned short* P, int row, int q) {
  return *(const bf16x8*)&P[row * 128 + ((q ^ (row & 7)) << 3)];
}

// ---- BK=32 staging (gemm/hatt): 128 rows x 32 cols, 512 chunks, 2/thread ----
DEV void stage32(const unsigned short* src, int ld, unsigned short* lds, int tid) {
#pragma unroll
  for (int i = 0; i < 2; ++i) {
    int c = i * 256 + tid;                 // wave-contiguous chunks
    int r = c >> 2, ck = c & 3;
    int col8 = ((ck ^ (r & 3)) << 3);      // pre-swizzled global column
    gll16(src + (long)r * ld + col8, (char*)lds + (size_t)c * 16);
  }
}
DEV bf16x8 frag32(const unsigned short* ls, int row, int q) {
  return *(const bf16x8*)&ls[row * 32 + ((q ^ (row & 3)) << 3)];
}

// C(M,N) = A(M,K) @ Bt(N,K)^T; bf16 in, fp32 acc; BK=32 depth-1 prefetch dbuf
template<int OUT_BF16>
__global__ __launch_bounds__(256, 4) void gemm_nt(
    const unsigned short* __restrict__ A, const unsigned short* __restrict__ Bt,
    void* __restrict__ C, int lda, int ldb, int ldc, int K,
    long sA, long sB, long sC, int gx, int gy)
{
  __shared__ __align__(16) unsigned short lsA[2][128 * 32];
  __shared__ __align__(16) unsigned short lsB[2][128 * 32];
  const int tid = threadIdx.x;
  const int w = tid >> 6, lane = tid & 63;
  const int wm = w >> 1, wn = w & 1;
  const int g = lane >> 4, r = lane & 15;
  const int wg = xcd_swz(blockIdx.x, gridDim.x);
  const int bz = wg / (gx * gy);
  const int r2 = wg - bz * gx * gy;
  const int by = r2 / gx;
  const int bx = r2 - by * gx;
  const long zb = bz;
  const unsigned short* Ab = A + zb * sA + (long)bx * 128 * lda;
  const unsigned short* Bb = Bt + zb * sB + (long)by * 128 * ldb;

  const int nt = K >> 5;
  stage32(Ab, lda, lsA[0], tid);
  stage32(Bb, ldb, lsB[0], tid);
  f32x4 acc[4][4] = {};
  for (int t = 0; t < nt; ++t) {
    __syncthreads();                       // stage(t) landed; prev reads done
    if (t + 1 < nt) {
      stage32(Ab + (t + 1) * 32, lda, lsA[(t + 1) & 1], tid);
      stage32(Bb + (t + 1) * 32, ldb, lsB[(t + 1) & 1], tid);
    }
    const unsigned short* la = lsA[t & 1];
    const unsigned short* lb = lsB[t & 1];
    bf16x8 af[4], bfr[4];
#pragma unroll
    for (int mi = 0; mi < 4; ++mi) af[mi]  = frag32(la, wm * 64 + mi * 16 + r, g);
#pragma unroll
    for (int ni = 0; ni < 4; ++ni) bfr[ni] = frag32(lb, wn * 64 + ni * 16 + r, g);
#pragma unroll
    for (int mi = 0; mi < 4; ++mi)
#pragma unroll
      for (int ni = 0; ni < 4; ++ni)
        acc[mi][ni] = __builtin_amdgcn_mfma_f32_16x16x32_bf16(af[mi], bfr[ni], acc[mi][ni], 0, 0, 0);
  }
  const int row0 = bx * 128 + wm * 64;
  const int col0 = by * 128 + wn * 64;
#pragma unroll
  for (int mi = 0; mi < 4; ++mi)
#pragma unroll
    for (int ni = 0; ni < 4; ++ni)
#pragma unroll
      for (int j = 0; j < 4; ++j) {
        int rr = row0 + mi * 16 + g * 4 + j;
        int cc = col0 + ni * 16 + r;
        float v = acc[mi][ni][j];
        if (OUT_BF16)
          ((unsigned short*)C)[zb * sC + (long)rr * ldc + cc] = f2bf(v);
        else
          ((float*)C)[zb * sC + (long)rr * ldc + cc] = v;
      }
}

// fused attflat MLP: logit[m] += sum_n relu(A@W1t^T + b1)[m,n] * W2[n]
__global__ __launch_bounds__(256, 4) void hatt_k(
    const unsigned short* __restrict__ A, const unsigned short* __restrict__ Bt,
    const float* __restrict__ b1, const float* __restrict__ W2,
    float* __restrict__ outlogit)
{
  constexpr int NH = H / 128;
  __shared__ __align__(16) unsigned short lsA[2][128 * 32];
  __shared__ __align__(16) unsigned short lsB[2][128 * 32];
  __shared__ float b1c[128], w2c[128];
  const int tid = threadIdx.x;
  const int w = tid >> 6, lane = tid & 63;
  const int wm = w >> 1, wn = w & 1;
  const int g = lane >> 4, r = lane & 15;
  const int wg = xcd_swz(blockIdx.x, gridDim.x);
  const int n0 = (wg % NH) * 128;
  const int m0 = (wg / NH) * 128;
  if (tid < 128) { b1c[tid] = b1[n0 + tid]; w2c[tid] = W2[n0 + tid]; }
  const unsigned short* Ab = A + (long)m0 * D;
  const unsigned short* Bb = Bt + (long)n0 * D;

  constexpr int NT = D / 32;
  stage32(Ab, D, lsA[0], tid);
  stage32(Bb, D, lsB[0], tid);
  f32x4 acc[4][4] = {};
  for (int t = 0; t < NT; ++t) {
    __syncthreads();
    if (t + 1 < NT) {
      stage32(Ab + (t + 1) * 32, D, lsA[(t + 1) & 1], tid);
      stage32(Bb + (t + 1) * 32, D, lsB[(t + 1) & 1], tid);
    }
    const unsigned short* la = lsA[t & 1];
    const unsigned short* lb = lsB[t & 1];
    bf16x8 af[4], bfr[4];
#pragma unroll
    for (int mi = 0; mi < 4; ++mi) af[mi]  = frag32(la, wm * 64 + mi * 16 + r, g);
#pragma unroll
    for (int ni = 0; ni < 4; ++ni) bfr[ni] = frag32(lb, wn * 64 + ni * 16 + r, g);
#pragma unroll
    for (int mi = 0; mi < 4; ++mi)
#pragma unroll
      for (int ni = 0; ni < 4; ++ni)
        acc[mi][ni] = __builtin_amdgcn_mfma_f32_16x16x32_bf16(af[mi], bfr[ni], acc[mi][ni], 0, 0, 0);
  }
  float rs[4][4];
#pragma unroll
  for (int mi = 0; mi < 4; ++mi)
#pragma unroll
    for (int j = 0; j < 4; ++j) rs[mi][j] = 0.f;
#pragma unroll
  for (int mi = 0; mi < 4; ++mi)
#pragma unroll
    for (int ni = 0; ni < 4; ++ni)
#pragma unroll
      for (int j = 0; j < 4; ++j) {
        int cl = wn * 64 + ni * 16 + r;
        float h = acc[mi][ni][j] + b1c[cl];
        h = fmaxf(h, 0.f);
        rs[mi][j] += h * w2c[cl];
      }
#pragma unroll
  for (int mi = 0; mi < 4; ++mi)
#pragma unroll
    for (int j = 0; j < 4; ++j) {
      float v = rs[mi][j];
      v += __shfl_xor(v, 1); v += __shfl_xor(v, 2);
      v += __shfl_xor(v, 4); v += __shfl_xor(v, 8);
      if (r == 0) atomicAdd(&outlogit[m0 + wm * 64 + mi * 16 + g * 4 + j], v);
    }
}

// fused dir-1 attention: x1-tile = softmax(mask(Q@K^T*SCALE)) @ V
__global__ __launch_bounds__(256, 2) void fattn1_k(
    const unsigned short* __restrict__ Qm,   // i_bf  (B,NI,D)
    const unsigned short* __restrict__ Km,   // q_bf  (B,NQ,D)
    const unsigned short* __restrict__ Vt,   // q_bfT (B,D,NQ)
    const int* __restrict__ mask,            // (B,NQ)
    unsigned short* __restrict__ O)          // x1 (B,NI,D)
{
  __shared__ __align__(16) unsigned short sh[64 * 64 + 128 * 64]; // Q|K, later P
  __shared__ __align__(16) unsigned short lsV[2][128 * 64];
  __shared__ float red0[64][2], red1[64][2];
  unsigned short* lsQ = sh;
  unsigned short* lsK = sh + 64 * 64;
  unsigned short* Pl  = sh;
  const int tid = threadIdx.x;
  const int w = tid >> 6, lane = tid & 63;
  const int wm = w >> 1, wn = w & 1;
  const int g = lane >> 4, r = lane & 15;
  const int wg = xcd_swz(blockIdx.x, gridDim.x);
  const int mt = wg & 7, b = wg >> 3;
  const unsigned short* Qb = Qm + ((long)b * NI + (long)mt * 64) * D;
  const unsigned short* Kb = Km + (long)b * NQ * D;
  const unsigned short* Vb = Vt + (long)b * D * NQ;

  int mki[4];
#pragma unroll
  for (int ni = 0; ni < 4; ++ni) mki[ni] = mask[b * NQ + wn * 64 + ni * 16 + r];

  f32x4 acc[2][4] = {};
  for (int k0 = 0; k0 < D; k0 += 64) {
    stageT<64>(Qb + k0, D, lsQ, tid);
    stageT<128>(Kb + k0, D, lsK, tid);
    __syncthreads();
#pragma unroll
    for (int kk = 0; kk < 2; ++kk) {
      bf16x8 af[2], bfr[4];
#pragma unroll
      for (int mi = 0; mi < 2; ++mi) af[mi]  = frag(lsQ, wm * 32 + mi * 16 + r, kk * 4 + g);
#pragma unroll
      for (int ni = 0; ni < 4; ++ni) bfr[ni] = frag(lsK, wn * 64 + ni * 16 + r, kk * 4 + g);
#pragma unroll
      for (int mi = 0; mi < 2; ++mi)
#pragma unroll
        for (int ni = 0; ni < 4; ++ni)
          acc[mi][ni] = __builtin_amdgcn_mfma_f32_16x16x32_bf16(af[mi], bfr[ni], acc[mi][ni], 0, 0, 0);
    }
    __syncthreads();
  }

  float x[2][4][4], pm[2][4];
#pragma unroll
  for (int mi = 0; mi < 2; ++mi)
#pragma unroll
    for (int j = 0; j < 4; ++j) pm[mi][j] = -3.4e38f;
#pragma unroll
  for (int mi = 0; mi < 2; ++mi)
#pragma unroll
    for (int ni = 0; ni < 4; ++ni)
#pragma unroll
      for (int j = 0; j < 4; ++j) {
        float v = mki[ni] ? NEGV : acc[mi][ni][j] * SCALE;
        x[mi][ni][j] = v;
        pm[mi][j] = fmaxf(pm[mi][j], v);
      }
#pragma unroll
  for (int s = 1; s < 16; s <<= 1)
#pragma unroll
    for (int mi = 0; mi < 2; ++mi)
#pragma unroll
      for (int j = 0; j < 4; ++j) pm[mi][j] = fmaxf(pm[mi][j], __shfl_xor(pm[mi][j], s));
  if (r == 0) {
#pragma unroll
    for (int mi = 0; mi < 2; ++mi)
#pragma unroll
      for (int j = 0; j < 4; ++j) red0[wm * 32 + mi * 16 + g * 4 + j][wn] = pm[mi][j];
  }
  __syncthreads();
  float mx[2][4], ps[2][4];
#pragma unroll
  for (int mi = 0; mi < 2; ++mi)
#pragma unroll
    for (int j = 0; j < 4; ++j) {
      int rl = wm * 32 + mi * 16 + g * 4 + j;
      mx[mi][j] = fmaxf(red0[rl][0], red0[rl][1]);
      ps[mi][j] = 0.f;
    }
#pragma unroll
  for (int mi = 0; mi < 2; ++mi)
#pragma unroll
    for (int ni = 0; ni < 4; ++ni)
#pragma unroll
      for (int j = 0; j < 4; ++j) {
        float e = __expf(x[mi][ni][j] - mx[mi][j]);
        x[mi][ni][j] = e;
        ps[mi][j] += e;
      }
#pragma unroll
  for (int s = 1; s < 16; s <<= 1)
#pragma unroll
    for (int mi = 0; mi < 2; ++mi)
#pragma unroll
      for (int j = 0; j < 4; ++j) ps[mi][j] += __shfl_xor(ps[mi][j], s);
  if (r == 0) {
#pragma unroll
    for (int mi = 0; mi < 2; ++mi)
#pragma unroll
      for (int j = 0; j < 4; ++j) red1[wm * 32 + mi * 16 + g * 4 + j][wn] = ps[mi][j];
  }
  __syncthreads();
#pragma unroll
  for (int mi = 0; mi < 2; ++mi)
#pragma unroll
    for (int j = 0; j < 4; ++j) {
      int rl = wm * 32 + mi * 16 + g * 4 + j;
      float inv = 1.f / (red1[rl][0] + red1[rl][1]);
#pragma unroll
      for (int ni = 0; ni < 4; ++ni) {
        int col = wn * 64 + ni * 16 + r;
        Pl[rl * 128 + (((col >> 3) ^ (rl & 7)) << 3) + (col & 7)] = f2bf(x[mi][ni][j] * inv);
      }
    }
  stageT<128>(Vb, 128, lsV[0], tid);
  stageT<128>(Vb + 64, 128, lsV[1], tid);
  __syncthreads();

  for (int nc = 0; nc < 5; ++nc) {
    if (nc > 0) __syncthreads();
    f32x4 po[2][4] = {};
#pragma unroll
    for (int kk2 = 0; kk2 < 2; ++kk2)
#pragma unroll
      for (int kk = 0; kk < 2; ++kk) {
        bf16x8 af[2], bfr[4];
#pragma unroll
        for (int mi = 0; mi < 2; ++mi) af[mi]  = fragP(Pl, wm * 32 + mi * 16 + r, kk2 * 8 + kk * 4 + g);
#pragma unroll
        for (int ni = 0; ni < 4; ++ni) bfr[ni] = frag(lsV[kk2], wn * 64 + ni * 16 + r, kk * 4 + g);
#pragma unroll
        for (int mi = 0; mi < 2; ++mi)
#pragma unroll
          for (int ni = 0; ni < 4; ++ni)
            po[mi][ni] = __builtin_amdgcn_mfma_f32_16x16x32_bf16(af[mi], bfr[ni], po[mi][ni], 0, 0, 0);
      }
    __syncthreads();
    if (nc < 4) {
      const unsigned short* Vn = Vb + (long)(nc + 1) * 128 * 128;
      stageT<128>(Vn, 128, lsV[0], tid);
      stageT<128>(Vn + 64, 128, lsV[1], tid);
    }
#pragma unroll
    for (int mi = 0; mi < 2; ++mi)
#pragma unroll
      for (int ni = 0; ni < 4; ++ni)
#pragma unroll
        for (int j = 0; j < 4; ++j) {
          int rr = mt * 64 + wm * 32 + mi * 16 + g * 4 + j;
          int cc = nc * 128 + wn * 64 + ni * 16 + r;
          O[((long)b * NI + rr) * D + cc] = f2bf(po[mi][ni][j]);
        }
  }
}

// masked row softmax over fp32 scores (one wave per row), writes bf16 P (dir 2)
template<int L>
__global__ void sm_scores(const float* __restrict__ S, const int* __restrict__ mask,
                          unsigned short* __restrict__ P, int M)
{
  constexpr int NV = L / 64;
  const int wid = threadIdx.x >> 6, lane = threadIdx.x & 63;
  const long row = (long)blockIdx.x * 4 + wid;
  const int b = (int)(row / M);
  const float* s = S + row * (long)L;
  const int* mk = mask + (long)b * L;
  float x[NV];
  float mx = -__builtin_inff();
#pragma unroll
  for (int i = 0; i < NV; ++i) {
    int idx = i * 64 + lane;
    float v = s[idx] * SCALE;
    x[i] = mk[idx] ? NEGV : v;
    mx = fmaxf(mx, x[i]);
  }
#pragma unroll
  for (int sft = 32; sft >= 1; sft >>= 1) mx = fmaxf(mx, __shfl_xor(mx, sft));
  float sum = 0.f;
#pragma unroll
  for (int i = 0; i < NV; ++i) { x[i] = __expf(x[i] - mx); sum += x[i]; }
#pragma unroll
  for (int sft = 32; sft >= 1; sft >>= 1) sum += __shfl_xor(sum, sft);
  const float inv = 1.f / sum;
  unsigned short* p = P + row * (long)L;
#pragma unroll
  for (int i = 0; i < NV; ++i) p[i * 64 + lane] = f2bf(x[i] * inv);
}

// tail part 1: att = softmax(mask(logit+b2)) (recomputed per block);
// pooled d-slice = sum_m att[m]*X[b,m,d]. grid (B, D/128), 512 thr.
template<int L>
__global__ __launch_bounds__(512, 2) void tail1_k(
    const float* __restrict__ logit, const int* __restrict__ mask,
    const float* __restrict__ b2p, const unsigned short* __restrict__ X,
    float* __restrict__ pooled, float* __restrict__ iw)
{
  __shared__ float att[L];
  __shared__ float red[8];
  __shared__ float part[4][128];
  const int tid = threadIdx.x, b = blockIdx.x;
  const int lane = tid & 63, wv = tid >> 6;
  const float b2v = b2p[0];
  float v = -__builtin_inff();
  if (tid < L) v = mask[(long)b * L + tid] ? NEGV : (logit[(long)b * L + tid] + b2v);
  float m = v;
#pragma unroll
  for (int s = 32; s >= 1; s >>= 1) m = fmaxf(m, __shfl_xor(m, s));
  if (lane == 0) red[wv] = m;
  __syncthreads();
  float mx = red[0];
#pragma unroll
  for (int i = 1; i < 8; ++i) mx = fmaxf(mx, red[i]);
  __syncthreads();
  float e = (tid < L) ? __expf(v - mx) : 0.f;
  float ssum = e;
#pragma unroll
  for (int s = 32; s >= 1; s >>= 1) ssum += __shfl_xor(ssum, s);
  if (lane == 0) red[wv] = ssum;
  __syncthreads();
  float tot = 0.f;
#pragma unroll
  for (int i = 0; i < 8; ++i) tot += red[i];
  const float a = e / tot;
  if (tid < L) {
    att[tid] = a;
    if (iw && blockIdx.y == 0) iw[(long)b * L + tid] = a;
  }
  __syncthreads();
  const int d = blockIdx.y * 128 + (tid & 127);
  const int grp = tid >> 7;                 // 0..3
  const unsigned short* Xb = X + (long)b * L * D + d;
  float s = 0.f;
  const int m0 = grp * (L / 4);
#pragma unroll 4
  for (int m2 = m0; m2 < m0 + L / 4; ++m2) s += att[m2] * bf2f(Xb[(long)m2 * D]);
  part[grp][tid & 127] = s;
  __syncthreads();
  if (tid < 128)
    pooled[(long)b * D + blockIdx.y * 128 + tid] =
        part[0][tid] + part[1][tid] + part[2][tid] + part[3][tid];
}

// tail part 2: out[b,n] = bm[n] + sum_k pooled[b,k]*Wm[k,n]. grid (B, D/128), 512 thr.
__global__ __launch_bounds__(512, 2) void tail2_k(
    const float* __restrict__ pooled, const float* __restrict__ W,
    const float* __restrict__ bias, float* __restrict__ out)
{
  __shared__ float p[D];
  __shared__ float part[4][128];
  const int tid = threadIdx.x, b = blockIdx.x;
  const int n = blockIdx.y * 128 + (tid & 127);
  const int kg = tid >> 7;                  // 0..3
  for (int i = tid; i < D; i += 512) p[i] = pooled[(long)b * D + i];
  __syncthreads();
  float acc = 0.f;
  const int k0 = kg * (D / 4);
#pragma unroll 4
  for (int k = k0; k < k0 + D / 4; ++k) acc += p[k] * W[(long)k * D + n];
  part[kg][tid & 127] = acc;
  __syncthreads();
  if (tid < 128)
    out[(long)b * D + blockIdx.y * 128 + tid] =
        bias[blockIdx.y * 128 + tid] + part[0][tid] + part[1][tid] + part[2][tid] + part[3][tid];
}

// 64x64 tile cast: read f32 once (float4), emit row-major bf16 (opt) + transposed bf16
template<int WRITE_N>
__global__ void cast_t_k(const float* __restrict__ in, unsigned short* __restrict__ outN,
                         unsigned short* __restrict__ outT, int R, int C)
{
  __shared__ float t[64][65];
  const int tid = threadIdx.x;
  const int cg = tid & 15, rw = tid >> 4;
  const long base = (long)blockIdx.z * R * C;
  const int c0 = blockIdx.x * 64, r0 = blockIdx.y * 64;
#pragma unroll
  for (int p = 0; p < 4; ++p) {
    int row = p * 16 + rw;
    float4 v = *(const float4*)&in[base + (long)(r0 + row) * C + c0 + cg * 4];
    *(float4*)&t[row][cg * 4] = v;
    if (WRITE_N) {
      ushort4 o;
      o.x = f2bf(v.x); o.y = f2bf(v.y); o.z = f2bf(v.z); o.w = f2bf(v.w);
      *(ushort4*)&outN[base + (long)(r0 + row) * C + c0 + cg * 4] = o;
    }
  }
  __syncthreads();
#pragma unroll
  for (int p = 0; p < 4; ++p) {
    int ocol = p * 16 + rw;
    ushort4 o;
    o.x = f2bf(t[cg * 4 + 0][ocol]);
    o.y = f2bf(t[cg * 4 + 1][ocol]);
    o.z = f2bf(t[cg * 4 + 2][ocol]);
    o.w = f2bf(t[cg * 4 + 3][ocol]);
    *(ushort4*)&outT[base + (long)(c0 + ocol) * R + r0 + cg * 4] = o;
  }
}

extern "C" void kernel_launch(void* const* d_in, const int* in_sizes, int n_in,
                              void* d_out, int out_size, void* d_ws, size_t ws_size,
                              hipStream_t stream)
{
  (void)in_sizes; (void)n_in; (void)out_size; (void)ws_size;
  const float* i_batch = (const float*)d_in[0];
  const float* q_batch = (const float*)d_in[1];
  const int*   i_mask  = (const int*)d_in[2];
  const int*   q_mask  = (const int*)d_in[3];
  const float* lW1 = (const float*)d_in[4];
  const float* lb1 = (const float*)d_in[5];
  const float* lW2 = (const float*)d_in[6];
  const float* lb2 = (const float*)d_in[7];
  const float* lWm = (const float*)d_in[8];
  const float* lbm = (const float*)d_in[9];
  const float* iW1 = (const float*)d_in[10];
  const float* ib1 = (const float*)d_in[11];
  const float* iW2 = (const float*)d_in[12];
  const float* ib2 = (const float*)d_in[13];
  const float* iWm = (const float*)d_in[14];
  const float* ibm = (const float*)d_in[15];
  float* out_if = (float*)d_out;          // (64,640)
  float* out_lf = out_if + B * D;         // (64,640)
  float* out_iw = out_lf + B * D;         // (64,512)

  char* wp = (char*)d_ws;
  size_t off = 0;
  auto alloc = [&](size_t bytes) { void* p = wp + off; off += (bytes + 255) & ~(size_t)255; return p; };
  unsigned short* i_bf   = (unsigned short*)alloc((size_t)B * NI * D * 2);
  unsigned short* i_bfT  = (unsigned short*)alloc((size_t)B * NI * D * 2);
  unsigned short* q_bf   = (unsigned short*)alloc((size_t)B * NQ * D * 2);
  unsigned short* q_bfT  = (unsigned short*)alloc((size_t)B * NQ * D * 2);
  unsigned short* x1_bf  = (unsigned short*)alloc((size_t)B * NI * D * 2);
  unsigned short* x2_bf  = (unsigned short*)alloc((size_t)B * NQ * D * 2);
  float*          scores = (float*)alloc((size_t)B * NQ * NI * 4);          // dir2 only
  unsigned short* p_bf   = (unsigned short*)alloc((size_t)B * NQ * NI * 2); // dir2 only
  unsigned short* lW1t   = (unsigned short*)alloc((size_t)H * D * 2);
  unsigned short* iW1t   = (unsigned short*)alloc((size_t)H * D * 2);
  float* logit1  = (float*)alloc((size_t)B * NI * 4);
  float* logit2  = (float*)alloc((size_t)B * NQ * 4);
  float* pooled1 = (float*)alloc((size_t)B * D * 4);
  float* pooled2 = (float*)alloc((size_t)B * D * 4);

  // zero the atomic-accumulated logits (contiguous allocs)
  hipMemsetAsync(logit1, 0, (size_t)(B * NI + B * NQ) * 4, stream);

  // ---- prep: fused cast+transpose (read inputs once, vectorized) ----
  cast_t_k<1><<<dim3(D / 64, NI / 64, B), 256, 0, stream>>>(i_batch, i_bf, i_bfT, NI, D);
  cast_t_k<1><<<dim3(D / 64, NQ / 64, B), 256, 0, stream>>>(q_batch, q_bf, q_bfT, NQ, D);
  cast_t_k<0><<<dim3(H / 64, D / 64, 1), 256, 0, stream>>>(lW1, nullptr, lW1t, D, H);
  cast_t_k<0><<<dim3(H / 64, D / 64, 1), 256, 0, stream>>>(iW1, nullptr, iW1t, D, H);

  // ---- direction 1 ----
  fattn1_k<<<dim3(8 * B), 256, 0, stream>>>(i_bf, q_bf, q_bfT, q_mask, x1_bf);
  hatt_k<<<dim3((H / 128) * (B * NI / 128)), 256, 0, stream>>>(x1_bf, lW1t, lb1, lW2, logit1);
  tail1_k<NI><<<dim3(B, D / 128), 512, 0, stream>>>(logit1, i_mask, lb2, x1_bf, pooled1, out_iw);
  tail2_k<<<dim3(B, D / 128), 512, 0, stream>>>(pooled1, lWm, lbm, out_if);

  // ---- direction 2 ----
  gemm_nt<0><<<dim3((NQ / 128) * (NI / 128) * B), 256, 0, stream>>>(
      q_bf, i_bf, scores, D, D, NI, D, (long)NQ * D, (long)NI * D, (long)NQ * NI,
      NQ / 128, NI / 128);
  sm_scores<NI><<<dim3(B * NQ / 4), 256, 0, stream>>>(scores, i_mask, p_bf, NQ);
  gemm_nt<1><<<dim3((NQ / 128) * (D / 128) * B), 256, 0, stream>>>(
      p_bf, i_bfT, x2_bf, NI, NI, D, NI, (long)NQ * NI, (long)D * NI, (long)NQ * D,
      NQ / 128, D / 128);
  hatt_k<<<dim3((H / 128) * (B * NQ / 128)), 256, 0, stream>>>(x2_bf, iW1t, ib1, iW2, logit2);
  tail1_k<NQ><<<dim3(B, D / 128), 512, 0, stream>>>(logit2, q_mask, ib2, x2_bf, pooled2, nullptr);
  tail2_k<<<dim3(B, D / 128), 512, 0, stream>>>(pooled2, iWm, ibm, out_lf);
}